// Round 1
// baseline (4376.757 us; speedup 1.0000x reference)
//
#include <hip/hip_runtime.h>
#include <cmath>

#define HD __device__ __forceinline__

constexpr int B_ = 2, N_ = 8192, DIM_ = 256, H_ = 8, DH_ = 64, INNER_ = 512, NB_ = 256, FF_ = 1024, E_ = 131072;
constexpr float LNEPS_ = 1e-5f, KEPS_ = 1e-4f;
constexpr float DN_ = 0.35355339059327373f;   // 64^-0.25
constexpr float RATIO_ = 0.0625f;             // 256^-0.5

HD unsigned fenc(float f){ unsigned b = __float_as_uint(f); return (b & 0x80000000u) ? ~b : (b | 0x80000000u); }
HD float fdec(unsigned u){ return (u & 0x80000000u) ? __uint_as_float(u & 0x7FFFFFFFu) : __uint_as_float(~u); }
HD float gelu_tanh(float x){
  float t = tanhf(0.7978845608028654f * (x + 0.044715f * x * x * x));
  return 0.5f * x * (1.f + t);
}

// ---------------- GNN ----------------
__global__ void k_deg(const int* __restrict__ ei, const float* __restrict__ ew, float* __restrict__ deg){
  int e = blockIdx.x * 256 + threadIdx.x;
  if (e < E_) atomicAdd(&deg[ei[E_ + e]], ew[e]);
}

__global__ void k_dinv(const float* __restrict__ deg, float* __restrict__ dinv){
  int i = blockIdx.x * 256 + threadIdx.x;
  if (i < N_){ float d = deg[i]; dinv[i] = d > 0.f ? rsqrtf(fmaxf(d, 1e-12f)) : 0.f; }
}

__global__ void k_agg(const int* __restrict__ ei, const float* __restrict__ ew, const float* __restrict__ dinv,
                      const float* __restrict__ gemb, float* __restrict__ agg){
  int e = blockIdx.x; int d = threadIdx.x;
  int r = ei[e], c = ei[E_ + e];
  float en = dinv[r] * ew[e] * dinv[c];
  atomicAdd(&agg[c * DIM_ + d], gemb[r * DIM_ + d] * en);
}

// ---------------- z0 = emb + pos + go ----------------
__launch_bounds__(256)
__global__ void k_z0(const float* __restrict__ x, const float* __restrict__ w1, const float* __restrict__ b1,
                     const float* __restrict__ w2, const float* __restrict__ b2,
                     const float* __restrict__ pos, const float* __restrict__ agg,
                     const float* __restrict__ gw, const float* __restrict__ gb, float* __restrict__ z){
  __shared__ float hsh[2][8][DIM_];
  __shared__ float ash[8][DIM_];
  int n0 = blockIdx.x * 8; int d = threadIdx.x;
  #pragma unroll
  for (int r = 0; r < 8; r++){
    ash[r][d] = agg[(n0 + r) * DIM_ + d];
    hsh[0][r][d] = fmaxf(x[n0 + r] * w1[d] + b1[d], 0.f);
    hsh[1][r][d] = fmaxf(x[N_ + n0 + r] * w1[d] + b1[d], 0.f);
  }
  __syncthreads();
  float go[8] = {}, e0[8] = {}, e1[8] = {};
  for (int k = 0; k < DIM_; k++){
    float wgk = gw[k * DIM_ + d], w2k = w2[k * DIM_ + d];
    #pragma unroll
    for (int r = 0; r < 8; r++){
      go[r] += ash[r][k] * wgk;
      e0[r] += hsh[0][r][k] * w2k;
      e1[r] += hsh[1][r][k] * w2k;
    }
  }
  #pragma unroll
  for (int r = 0; r < 8; r++){
    float base = go[r] + gb[d] + pos[(n0 + r) * DIM_ + d] + b2[d];
    z[(n0 + r) * DIM_ + d]      = e0[r] + base;
    z[(N_ + n0 + r) * DIM_ + d] = e1[r] + base;
  }
}

// ---------------- LayerNorm ----------------
__launch_bounds__(256)
__global__ void k_ln(const float* __restrict__ z, const float* __restrict__ g, const float* __restrict__ bb,
                     float* __restrict__ y){
  int row = blockIdx.x, d = threadIdx.x;
  __shared__ float red[256];
  float v = z[row * DIM_ + d];
  red[d] = v; __syncthreads();
  #pragma unroll
  for (int s = 128; s > 0; s >>= 1){ if (d < s) red[d] += red[d + s]; __syncthreads(); }
  float mean = red[0] * (1.f / DIM_);
  __syncthreads();
  float c = v - mean;
  red[d] = c * c; __syncthreads();
  #pragma unroll
  for (int s = 128; s > 0; s >>= 1){ if (d < s) red[d] += red[d + s]; __syncthreads(); }
  float var = red[0] * (1.f / DIM_);
  y[row * DIM_ + d] = c * rsqrtf(var + LNEPS_) * g[d] + bb[d];
}

// ---------------- generic fp32 GEMM, 64x64 tile, 256 threads, 4x4/thread ----------------
// EPI: 0 = C = AB (+bias); 1 = C += AB (+bias) (residual, in-place); 2 = C = gelu(AB + bias)
template<int EPI>
__launch_bounds__(256)
__global__ void k_gemm(const float* __restrict__ A, const float* __restrict__ Bm,
                       const float* __restrict__ bias, float* __restrict__ C,
                       int M, int Nn, int K){
  __shared__ float As[16][68];
  __shared__ float Bs[16][64];
  int t = threadIdx.x;
  int tx = t & 15, ty = t >> 4;
  int m0 = blockIdx.x * 64, n0 = blockIdx.y * 64;
  int mrow = t >> 2, kq = t & 3;
  int krow = t >> 4, nq = t & 15;
  float acc[4][4] = {};
  for (int kt = 0; kt < K; kt += 16){
    float4 a4 = *(const float4*)&A[(m0 + mrow) * K + kt + kq * 4];
    As[kq * 4 + 0][mrow] = a4.x; As[kq * 4 + 1][mrow] = a4.y;
    As[kq * 4 + 2][mrow] = a4.z; As[kq * 4 + 3][mrow] = a4.w;
    *(float4*)&Bs[krow][nq * 4] = *(const float4*)&Bm[(kt + krow) * Nn + n0 + nq * 4];
    __syncthreads();
    #pragma unroll
    for (int k = 0; k < 16; k++){
      float4 av = *(const float4*)&As[k][ty * 4];
      float4 bv = *(const float4*)&Bs[k][tx * 4];
      acc[0][0] += av.x * bv.x; acc[0][1] += av.x * bv.y; acc[0][2] += av.x * bv.z; acc[0][3] += av.x * bv.w;
      acc[1][0] += av.y * bv.x; acc[1][1] += av.y * bv.y; acc[1][2] += av.y * bv.z; acc[1][3] += av.y * bv.w;
      acc[2][0] += av.z * bv.x; acc[2][1] += av.z * bv.y; acc[2][2] += av.z * bv.z; acc[2][3] += av.z * bv.w;
      acc[3][0] += av.w * bv.x; acc[3][1] += av.w * bv.y; acc[3][2] += av.w * bv.z; acc[3][3] += av.w * bv.w;
    }
    __syncthreads();
  }
  #pragma unroll
  for (int i = 0; i < 4; i++){
    int m = m0 + ty * 4 + i, n = n0 + tx * 4;
    float4 r = make_float4(acc[i][0], acc[i][1], acc[i][2], acc[i][3]);
    if (bias){ r.x += bias[n]; r.y += bias[n + 1]; r.z += bias[n + 2]; r.w += bias[n + 3]; }
    if (EPI == 1){
      float4 old = *(const float4*)&C[m * Nn + n];
      r.x += old.x; r.y += old.y; r.z += old.z; r.w += old.w;
    }
    if (EPI == 2){
      r.x = gelu_tanh(r.x); r.y = gelu_tanh(r.y); r.z = gelu_tanh(r.z); r.w = gelu_tanh(r.w);
    }
    *(float4*)&C[m * Nn + n] = r;
  }
}

// ---------------- favor-k pass 1: stab_k[b,h] = max over (n,m) of dd ----------------
__launch_bounds__(256)
__global__ void k_stab(const float* __restrict__ kb, const float* __restrict__ proj, unsigned* __restrict__ stab){
  int h = blockIdx.y, b = blockIdx.z, n0 = blockIdx.x * 128;
  int bh = b * H_ + h, t = threadIdx.x;
  __shared__ float ksh[128][68];
  __shared__ float red[256];
  #pragma unroll
  for (int it = 0; it < 8; ++it){
    int lin = it * 256 + t, r = lin >> 4, q4 = lin & 15;
    *(float4*)&ksh[r][q4 * 4] = *(const float4*)&kb[(b * N_ + n0 + r) * INNER_ + h * DH_ + q4 * 4];
  }
  float pr[64];
  #pragma unroll
  for (int q4 = 0; q4 < 16; q4++){
    float4 p = *(const float4*)&proj[t * DH_ + q4 * 4];
    pr[q4 * 4] = p.x; pr[q4 * 4 + 1] = p.y; pr[q4 * 4 + 2] = p.z; pr[q4 * 4 + 3] = p.w;
  }
  __syncthreads();
  float mx = -3.4e38f;
  for (int r = 0; r < 128; r++){
    float dd = 0.f;
    #pragma unroll
    for (int q4 = 0; q4 < 16; q4++){
      float4 kk = *(const float4*)&ksh[r][q4 * 4];
      dd += kk.x * pr[q4 * 4] + kk.y * pr[q4 * 4 + 1] + kk.z * pr[q4 * 4 + 2] + kk.w * pr[q4 * 4 + 3];
    }
    mx = fmaxf(mx, dd);
  }
  red[t] = mx; __syncthreads();
  #pragma unroll
  for (int s = 128; s > 0; s >>= 1){ if (t < s) red[t] = fmaxf(red[t], red[t + s]); __syncthreads(); }
  if (t == 0) atomicMax(&stab[bh], fenc(red[0] * DN_));
}

// ---------------- favor-k pass 2: ctx[b,h,m,:], kfsum[b,h,m] ----------------
__launch_bounds__(256)
__global__ void k_ctx(const float* __restrict__ kb, const float* __restrict__ vb, const float* __restrict__ proj,
                      const unsigned* __restrict__ stab, float* __restrict__ ctx, float* __restrict__ kfsum){
  int h = blockIdx.y, b = blockIdx.z, n0 = blockIdx.x * 128;
  int bh = b * H_ + h, t = threadIdx.x;
  __shared__ float ksh[128][68];
  __shared__ float vsh[128][68];
  __shared__ float diag[128];
  #pragma unroll
  for (int it = 0; it < 8; ++it){
    int lin = it * 256 + t, r = lin >> 4, q4 = lin & 15;
    *(float4*)&ksh[r][q4 * 4] = *(const float4*)&kb[(b * N_ + n0 + r) * INNER_ + h * DH_ + q4 * 4];
    *(float4*)&vsh[r][q4 * 4] = *(const float4*)&vb[(b * N_ + n0 + r) * INNER_ + h * DH_ + q4 * 4];
  }
  float pr[64];
  #pragma unroll
  for (int q4 = 0; q4 < 16; q4++){
    float4 p = *(const float4*)&proj[t * DH_ + q4 * 4];
    pr[q4 * 4] = p.x; pr[q4 * 4 + 1] = p.y; pr[q4 * 4 + 2] = p.z; pr[q4 * 4 + 3] = p.w;
  }
  __syncthreads();
  if (t < 128){
    float s = 0.f;
    for (int d2 = 0; d2 < 64; d2++){ float kv = ksh[t][d2]; s += kv * kv; }
    diag[t] = 0.5f * DN_ * DN_ * s;
  }
  __syncthreads();
  float st = fdec(stab[bh]);
  float cacc[64] = {};
  float ks = 0.f;
  for (int r = 0; r < 128; r++){
    float dd = 0.f;
    #pragma unroll
    for (int q4 = 0; q4 < 16; q4++){
      float4 kk = *(const float4*)&ksh[r][q4 * 4];
      dd += kk.x * pr[q4 * 4] + kk.y * pr[q4 * 4 + 1] + kk.z * pr[q4 * 4 + 2] + kk.w * pr[q4 * 4 + 3];
    }
    float kf = RATIO_ * (expf(dd * DN_ - diag[r] - st) + KEPS_);
    ks += kf;
    #pragma unroll
    for (int q4 = 0; q4 < 16; q4++){
      float4 vv = *(const float4*)&vsh[r][q4 * 4];
      cacc[q4 * 4]     += kf * vv.x;
      cacc[q4 * 4 + 1] += kf * vv.y;
      cacc[q4 * 4 + 2] += kf * vv.z;
      cacc[q4 * 4 + 3] += kf * vv.w;
    }
  }
  atomicAdd(&kfsum[bh * NB_ + t], ks);
  #pragma unroll
  for (int d2 = 0; d2 < 64; d2++) atomicAdd(&ctx[(bh * NB_ + t) * DH_ + d2], cacc[d2]);
}

// ---------------- favor-q fused: qf, denom, o = (qf @ ctx)/denom ----------------
__launch_bounds__(256)
__global__ void k_qo(const float* __restrict__ qb, const float* __restrict__ proj,
                     const float* __restrict__ ctxg, const float* __restrict__ kfsg, float* __restrict__ ob){
  int h = blockIdx.y, b = blockIdx.z, n0 = blockIdx.x * 64;
  int bh = b * H_ + h, t = threadIdx.x;
  __shared__ float qsh[64][68];
  __shared__ float qfsh[64][260];
  __shared__ float ctxsh[128][64];
  __shared__ float kfs[256];
  __shared__ float diag[64], rmax[64], den[64];
  __shared__ float rpart[64][4];
  #pragma unroll
  for (int it = 0; it < 4; ++it){
    int lin = it * 256 + t, r = lin >> 4, q4 = lin & 15;
    *(float4*)&qsh[r][q4 * 4] = *(const float4*)&qb[(b * N_ + n0 + r) * INNER_ + h * DH_ + q4 * 4];
  }
  kfs[t] = kfsg[bh * NB_ + t];
  float pr[64];
  #pragma unroll
  for (int q4 = 0; q4 < 16; q4++){
    float4 p = *(const float4*)&proj[t * DH_ + q4 * 4];
    pr[q4 * 4] = p.x; pr[q4 * 4 + 1] = p.y; pr[q4 * 4 + 2] = p.z; pr[q4 * 4 + 3] = p.w;
  }
  __syncthreads();
  if (t < 64){
    float s = 0.f;
    for (int d2 = 0; d2 < 64; d2++){ float qv = qsh[t][d2]; s += qv * qv; }
    diag[t] = 0.5f * DN_ * DN_ * s;
  }
  // phase B: dd for all 64 rows, this thread's feature column t
  for (int r = 0; r < 64; r++){
    float dd = 0.f;
    #pragma unroll
    for (int q4 = 0; q4 < 16; q4++){
      float4 kk = *(const float4*)&qsh[r][q4 * 4];
      dd += kk.x * pr[q4 * 4] + kk.y * pr[q4 * 4 + 1] + kk.z * pr[q4 * 4 + 2] + kk.w * pr[q4 * 4 + 3];
    }
    qfsh[r][t] = dd * DN_;
  }
  __syncthreads();
  // row max
  { int r = t >> 2, seg = t & 3; float mx = -3.4e38f;
    for (int i = 0; i < 64; i++) mx = fmaxf(mx, qfsh[r][seg * 64 + i]);
    rpart[r][seg] = mx; }
  __syncthreads();
  if (t < 64) rmax[t] = fmaxf(fmaxf(rpart[t][0], rpart[t][1]), fmaxf(rpart[t][2], rpart[t][3]));
  __syncthreads();
  // qf
  for (int r = 0; r < 64; r++){
    qfsh[r][t] = RATIO_ * (expf(qfsh[r][t] - diag[r] - rmax[r]) + KEPS_);
  }
  __syncthreads();
  // denom
  { int r = t >> 2, seg = t & 3; float s = 0.f;
    for (int i = 0; i < 64; i++) s += qfsh[r][seg * 64 + i] * kfs[seg * 64 + i];
    rpart[r][seg] = s; }
  __syncthreads();
  if (t < 64) den[t] = rpart[t][0] + rpart[t][1] + rpart[t][2] + rpart[t][3];
  // phase D: o = qf @ ctx (ctx streamed in 2 chunks of 128 features)
  int dq = t & 15, rg = t >> 4, rb = rg * 4;
  float acc[4][4] = {};
  for (int ch = 0; ch < 2; ++ch){
    __syncthreads();
    #pragma unroll
    for (int it = 0; it < 8; ++it){
      int lin = it * 256 + t, m = lin >> 4, q4 = lin & 15;
      *(float4*)&ctxsh[m][q4 * 4] = *(const float4*)&ctxg[(bh * NB_ + ch * 128 + m) * DH_ + q4 * 4];
    }
    __syncthreads();
    for (int m = 0; m < 128; m++){
      int mg = ch * 128 + m;
      float4 cv = *(const float4*)&ctxsh[m][dq * 4];
      float q0 = qfsh[rb][mg], q1 = qfsh[rb + 1][mg], q2 = qfsh[rb + 2][mg], q3 = qfsh[rb + 3][mg];
      acc[0][0] += q0 * cv.x; acc[0][1] += q0 * cv.y; acc[0][2] += q0 * cv.z; acc[0][3] += q0 * cv.w;
      acc[1][0] += q1 * cv.x; acc[1][1] += q1 * cv.y; acc[1][2] += q1 * cv.z; acc[1][3] += q1 * cv.w;
      acc[2][0] += q2 * cv.x; acc[2][1] += q2 * cv.y; acc[2][2] += q2 * cv.z; acc[2][3] += q2 * cv.w;
      acc[3][0] += q3 * cv.x; acc[3][1] += q3 * cv.y; acc[3][2] += q3 * cv.z; acc[3][3] += q3 * cv.w;
    }
  }
  #pragma unroll
  for (int rr = 0; rr < 4; rr++){
    float id = 1.f / den[rb + rr];
    float4 ov = make_float4(acc[rr][0] * id, acc[rr][1] * id, acc[rr][2] * id, acc[rr][3] * id);
    *(float4*)&ob[(b * N_ + n0 + rb + rr) * INNER_ + h * DH_ + dq * 4] = ov;
  }
}

// ---------------- final LN + head ----------------
__launch_bounds__(256)
__global__ void k_final(const float* __restrict__ z, const float* __restrict__ g, const float* __restrict__ bb,
                        const float* __restrict__ ow, const float* __restrict__ obias, float* __restrict__ out){
  int row = blockIdx.x, d = threadIdx.x;
  __shared__ float red[256];
  float v = z[row * DIM_ + d];
  red[d] = v; __syncthreads();
  #pragma unroll
  for (int s = 128; s > 0; s >>= 1){ if (d < s) red[d] += red[d + s]; __syncthreads(); }
  float mean = red[0] * (1.f / DIM_);
  __syncthreads();
  float c = v - mean;
  red[d] = c * c; __syncthreads();
  #pragma unroll
  for (int s = 128; s > 0; s >>= 1){ if (d < s) red[d] += red[d + s]; __syncthreads(); }
  float var = red[0] * (1.f / DIM_);
  __syncthreads();
  float yv = c * rsqrtf(var + LNEPS_) * g[d] + bb[d];
  red[d] = yv * ow[d]; __syncthreads();
  #pragma unroll
  for (int s = 128; s > 0; s >>= 1){ if (d < s) red[d] += red[d + s]; __syncthreads(); }
  if (d == 0) out[row] = red[0] + obias[0];
}

extern "C" void kernel_launch(void* const* d_in, const int* in_sizes, int n_in,
                              void* d_out, int out_size, void* d_ws, size_t ws_size,
                              hipStream_t stream){
  (void)in_sizes; (void)n_in; (void)out_size; (void)ws_size;
  const float* x      = (const float*)d_in[0];
  const float* mlp_w1 = (const float*)d_in[1];
  const float* mlp_b1 = (const float*)d_in[2];
  const float* mlp_w2 = (const float*)d_in[3];
  const float* mlp_b2 = (const float*)d_in[4];
  const float* pos    = (const float*)d_in[5];
  const float* gemb   = (const float*)d_in[6];
  const float* gw     = (const float*)d_in[7];
  const float* gb     = (const float*)d_in[8];
  const float* ew     = (const float*)d_in[9];
  const float* proj   = (const float*)d_in[10];
  const float* ln1g   = (const float*)d_in[11];
  const float* ln1b   = (const float*)d_in[12];
  const float* wq     = (const float*)d_in[13];
  const float* wk     = (const float*)d_in[14];
  const float* wv     = (const float*)d_in[15];
  const float* wo     = (const float*)d_in[16];
  const float* bo     = (const float*)d_in[17];
  const float* ln2g   = (const float*)d_in[18];
  const float* ln2b   = (const float*)d_in[19];
  const float* ffw1   = (const float*)d_in[20];
  const float* ffb1   = (const float*)d_in[21];
  const float* ffw2   = (const float*)d_in[22];
  const float* ffb2   = (const float*)d_in[23];
  const float* nfg    = (const float*)d_in[24];
  const float* nfb    = (const float*)d_in[25];
  const float* ow     = (const float*)d_in[26];
  const float* obias  = (const float*)d_in[27];
  const int*   ei     = (const int*)d_in[28];
  float* out = (float*)d_out;

  float* ws    = (float*)d_ws;
  float* deg   = ws;                       // 8192
  float* dinv  = deg + N_;                 // 8192
  unsigned* stab = (unsigned*)(dinv + N_); // 16 (padded to 256)
  float* kfsum = ws + 2 * N_ + 256;        // 4096
  float* ctx   = kfsum + B_ * H_ * NB_;            // 262144
  float* agg   = ctx + B_ * H_ * NB_ * DH_;        // 2097152
  float* z     = agg + N_ * DIM_;                  // 4194304
  float* y     = z + (size_t)B_ * N_ * DIM_;       // 4194304
  float* qb    = y + (size_t)B_ * N_ * DIM_;       // 8388608
  float* kb    = qb + (size_t)B_ * N_ * INNER_;    // 8388608
  float* vb    = kb + (size_t)B_ * N_ * INNER_;    // 8388608
  float* ffb   = qb;  // alias: q+k region = exactly B*N*FF
  float* ob    = vb;  // alias: v dead once ctx is computed

  hipMemsetAsync(deg, 0, N_ * sizeof(float), stream);
  hipMemsetAsync(agg, 0, (size_t)N_ * DIM_ * sizeof(float), stream);

  k_deg<<<E_ / 256, 256, 0, stream>>>(ei, ew, deg);
  k_dinv<<<N_ / 256, 256, 0, stream>>>(deg, dinv);
  k_agg<<<E_, 256, 0, stream>>>(ei, ew, dinv, gemb, agg);
  k_z0<<<N_ / 8, 256, 0, stream>>>(x, mlp_w1, mlp_b1, mlp_w2, mlp_b2, pos, agg, gw, gb, z);

  for (int l = 0; l < 2; ++l){
    hipMemsetAsync(stab, 0, 16 * sizeof(unsigned), stream);
    hipMemsetAsync(kfsum, 0, (size_t)B_ * H_ * NB_ * sizeof(float), stream);
    hipMemsetAsync(ctx, 0, (size_t)B_ * H_ * NB_ * DH_ * sizeof(float), stream);
    k_ln<<<B_ * N_, 256, 0, stream>>>(z, ln1g + l * DIM_, ln1b + l * DIM_, y);
    k_gemm<0><<<dim3(B_ * N_ / 64, INNER_ / 64), 256, 0, stream>>>(y, wq + (size_t)l * DIM_ * INNER_, nullptr, qb, B_ * N_, INNER_, DIM_);
    k_gemm<0><<<dim3(B_ * N_ / 64, INNER_ / 64), 256, 0, stream>>>(y, wk + (size_t)l * DIM_ * INNER_, nullptr, kb, B_ * N_, INNER_, DIM_);
    k_gemm<0><<<dim3(B_ * N_ / 64, INNER_ / 64), 256, 0, stream>>>(y, wv + (size_t)l * DIM_ * INNER_, nullptr, vb, B_ * N_, INNER_, DIM_);
    k_stab<<<dim3(N_ / 128, H_, B_), 256, 0, stream>>>(kb, proj, stab);
    k_ctx<<<dim3(N_ / 128, H_, B_), 256, 0, stream>>>(kb, vb, proj, stab, ctx, kfsum);
    k_qo<<<dim3(N_ / 64, H_, B_), 256, 0, stream>>>(qb, proj, ctx, kfsum, ob);
    k_gemm<1><<<dim3(B_ * N_ / 64, DIM_ / 64), 256, 0, stream>>>(ob, wo + (size_t)l * INNER_ * DIM_, bo + l * DIM_, z, B_ * N_, DIM_, INNER_);
    k_ln<<<B_ * N_, 256, 0, stream>>>(z, ln2g + l * DIM_, ln2b + l * DIM_, y);
    k_gemm<2><<<dim3(B_ * N_ / 64, FF_ / 64), 256, 0, stream>>>(y, ffw1 + (size_t)l * DIM_ * FF_, ffb1 + l * FF_, ffb, B_ * N_, FF_, DIM_);
    k_gemm<1><<<dim3(B_ * N_ / 64, DIM_ / 64), 256, 0, stream>>>(ffb, ffw2 + (size_t)l * FF_ * DIM_, ffb2 + l * DIM_, z, B_ * N_, DIM_, FF_);
  }
  k_final<<<B_ * N_, 256, 0, stream>>>(z, nfg, nfb, ow, obias, out);
}

// Round 3
// 3909.604 us; speedup vs baseline: 1.1195x; 1.1195x over previous
//
#include <hip/hip_runtime.h>
#include <cmath>

#define HD __device__ __forceinline__

constexpr int B_ = 2, N_ = 8192, DIM_ = 256, H_ = 8, DH_ = 64, INNER_ = 512, NB_ = 256, FF_ = 1024, E_ = 131072;
constexpr int CH_ = 16, ROWS_ = N_ / CH_;   // k_ctx chunking: 16 chunks x 512 rows
constexpr float LNEPS_ = 1e-5f, KEPS_ = 1e-4f;
constexpr float DN_ = 0.35355339059327373f;   // 64^-0.25
constexpr float RATIO_ = 0.0625f;             // 256^-0.5

typedef __attribute__((ext_vector_type(8))) __bf16 bf16x8;
typedef __attribute__((ext_vector_type(4))) float f32x4;

HD unsigned fenc(float f){ unsigned b = __float_as_uint(f); return (b & 0x80000000u) ? ~b : (b | 0x80000000u); }
HD float fdec(unsigned u){ return (u & 0x80000000u) ? __uint_as_float(u & 0x7FFFFFFFu) : __uint_as_float(~u); }
HD float gelu_tanh(float x){
  float t = tanhf(0.7978845608028654f * (x + 0.044715f * x * x * x));
  return 0.5f * x * (1.f + t);
}
HD void gload16(const void* g, void* l){
  __builtin_amdgcn_global_load_lds((const __attribute__((address_space(1))) void*)g,
                                   (__attribute__((address_space(3))) void*)l, 16, 0, 0);
}

// ---------------- GNN ----------------
__global__ void k_deg(const int* __restrict__ ei, const float* __restrict__ ew, float* __restrict__ deg){
  int e = blockIdx.x * 256 + threadIdx.x;
  if (e < E_) atomicAdd(&deg[ei[E_ + e]], ew[e]);
}

__global__ void k_dinv(const float* __restrict__ deg, float* __restrict__ dinv){
  int i = blockIdx.x * 256 + threadIdx.x;
  if (i < N_){ float d = deg[i]; dinv[i] = d > 0.f ? rsqrtf(fmaxf(d, 1e-12f)) : 0.f; }
}

__global__ void k_agg(const int* __restrict__ ei, const float* __restrict__ ew, const float* __restrict__ dinv,
                      const float* __restrict__ gemb, float* __restrict__ agg){
  int e = blockIdx.x; int d = threadIdx.x;
  int r = ei[e], c = ei[E_ + e];
  float en = dinv[r] * ew[e] * dinv[c];
  atomicAdd(&agg[c * DIM_ + d], gemb[r * DIM_ + d] * en);
}

// ---------------- z0 = emb + pos + go ----------------
__launch_bounds__(256)
__global__ void k_z0(const float* __restrict__ x, const float* __restrict__ w1, const float* __restrict__ b1,
                     const float* __restrict__ w2, const float* __restrict__ b2,
                     const float* __restrict__ pos, const float* __restrict__ agg,
                     const float* __restrict__ gw, const float* __restrict__ gb, float* __restrict__ z){
  __shared__ float hsh[2][8][DIM_];
  __shared__ float ash[8][DIM_];
  int n0 = blockIdx.x * 8; int d = threadIdx.x;
  #pragma unroll
  for (int r = 0; r < 8; r++){
    ash[r][d] = agg[(n0 + r) * DIM_ + d];
    hsh[0][r][d] = fmaxf(x[n0 + r] * w1[d] + b1[d], 0.f);
    hsh[1][r][d] = fmaxf(x[N_ + n0 + r] * w1[d] + b1[d], 0.f);
  }
  __syncthreads();
  float go[8] = {}, e0[8] = {}, e1[8] = {};
  for (int k = 0; k < DIM_; k++){
    float wgk = gw[k * DIM_ + d], w2k = w2[k * DIM_ + d];
    #pragma unroll
    for (int r = 0; r < 8; r++){
      go[r] += ash[r][k] * wgk;
      e0[r] += hsh[0][r][k] * w2k;
      e1[r] += hsh[1][r][k] * w2k;
    }
  }
  #pragma unroll
  for (int r = 0; r < 8; r++){
    float base = go[r] + gb[d] + pos[(n0 + r) * DIM_ + d] + b2[d];
    z[(n0 + r) * DIM_ + d]      = e0[r] + base;
    z[(N_ + n0 + r) * DIM_ + d] = e1[r] + base;
  }
}

// ---------------- LayerNorm (bf16 out) ----------------
__launch_bounds__(256)
__global__ void k_ln(const float* __restrict__ z, const float* __restrict__ g, const float* __restrict__ bb,
                     __bf16* __restrict__ y){
  int row = blockIdx.x, d = threadIdx.x;
  __shared__ float red[256];
  float v = z[row * DIM_ + d];
  red[d] = v; __syncthreads();
  #pragma unroll
  for (int s = 128; s > 0; s >>= 1){ if (d < s) red[d] += red[d + s]; __syncthreads(); }
  float mean = red[0] * (1.f / DIM_);
  __syncthreads();
  float c = v - mean;
  red[d] = c * c; __syncthreads();
  #pragma unroll
  for (int s = 128; s > 0; s >>= 1){ if (d < s) red[d] += red[d + s]; __syncthreads(); }
  float var = red[0] * (1.f / DIM_);
  y[row * DIM_ + d] = (__bf16)(c * rsqrtf(var + LNEPS_) * g[d] + bb[d]);
}

// ---------------- weight transpose+convert: src[K][N] f32 -> dst[N][K] bf16 ----------------
__launch_bounds__(256)
__global__ void k_convT(const float* __restrict__ src, __bf16* __restrict__ dst, int K, int N){
  __shared__ float tile[32][33];
  int kb0 = blockIdx.x * 32, nb0 = blockIdx.y * 32;
  int tx = threadIdx.x & 31, ty = threadIdx.x >> 5;
  #pragma unroll
  for (int i = 0; i < 32; i += 8)
    tile[ty + i][tx] = src[(size_t)(kb0 + ty + i) * N + nb0 + tx];
  __syncthreads();
  #pragma unroll
  for (int i = 0; i < 32; i += 8)
    dst[(size_t)(nb0 + ty + i) * K + kb0 + tx] = (__bf16)tile[tx][ty + i];
}

// ---------------- bf16 MFMA GEMM: C[M][N] = A[M][K] @ BT[N][K]^T ----------------
// EPI: 0 = C f32 = AB (+bias if non-null); 1 = C f32 += AB + bias (residual);
//      2 = Cb bf16 = gelu(AB + bias);      3 = Cb bf16 = AB
template<int EPI>
__launch_bounds__(256)
__global__ void k_gemm_bt(const __bf16* __restrict__ A, const __bf16* __restrict__ BT,
                          const float* __restrict__ bias, float* __restrict__ C,
                          __bf16* __restrict__ Cb, int M, int Nn, int K){
  __shared__ __align__(16) __bf16 As[128 * 64];
  __shared__ __align__(16) __bf16 Bs[128 * 64];
  int t = threadIdx.x;
  int w = t >> 6, l = t & 63;
  int m0 = blockIdx.x * 128, n0 = blockIdx.y * 128;
  int wm = w >> 1, wn = w & 1;
  int lr = l & 15, lk = (l >> 4) * 8;
  f32x4 acc[4][4];
  #pragma unroll
  for (int i = 0; i < 4; ++i)
    #pragma unroll
    for (int j = 0; j < 4; ++j) acc[i][j] = 0.f;

  for (int kt = 0; kt < K; kt += 64){
    #pragma unroll
    for (int c = 0; c < 4; ++c){
      int chunk = c * 256 + w * 64 + l;          // per-lane chunk id
      int row = chunk >> 3, off = (chunk & 7) * 8;
      int ldsbase = (c * 256 + w * 64) * 8;       // wave-uniform; HW adds lane*16B
      gload16(A + (size_t)(m0 + row) * K + kt + off, (void*)(As + ldsbase));
      gload16(BT + (size_t)(n0 + row) * K + kt + off, (void*)(Bs + ldsbase));
    }
    asm volatile("s_waitcnt vmcnt(0)" ::: "memory");
    __syncthreads();
    #pragma unroll
    for (int kk = 0; kk < 2; ++kk){
      bf16x8 af[4], bfr[4];
      #pragma unroll
      for (int i = 0; i < 4; ++i)
        af[i] = *(const bf16x8*)&As[(wm * 64 + i * 16 + lr) * 64 + kk * 32 + lk];
      #pragma unroll
      for (int j = 0; j < 4; ++j)
        bfr[j] = *(const bf16x8*)&Bs[(wn * 64 + j * 16 + lr) * 64 + kk * 32 + lk];
      #pragma unroll
      for (int i = 0; i < 4; ++i)
        #pragma unroll
        for (int j = 0; j < 4; ++j)
          acc[i][j] = __builtin_amdgcn_mfma_f32_16x16x32_bf16(af[i], bfr[j], acc[i][j], 0, 0, 0);
    }
    __syncthreads();
  }
  int cr = (l >> 4) * 4;
  #pragma unroll
  for (int i = 0; i < 4; ++i){
    #pragma unroll
    for (int j = 0; j < 4; ++j){
      int row = m0 + wm * 64 + i * 16 + cr;
      int col = n0 + wn * 64 + j * 16 + lr;
      float bv = bias ? bias[col] : 0.f;
      #pragma unroll
      for (int r = 0; r < 4; ++r){
        float v = acc[i][j][r] + bv;
        if (EPI == 0) C[(size_t)(row + r) * Nn + col] = v;
        if (EPI == 1) C[(size_t)(row + r) * Nn + col] += v;
        if (EPI == 2) Cb[(size_t)(row + r) * Nn + col] = (__bf16)gelu_tanh(v);
        if (EPI == 3) Cb[(size_t)(row + r) * Nn + col] = (__bf16)v;
      }
    }
  }
}

// ---------------- favor-k pass 1: stab_k[b,h] = max over (n,m) of dd*DN ----------------
__launch_bounds__(256)
__global__ void k_stab(const float* __restrict__ kb, const float* __restrict__ proj, unsigned* __restrict__ stab){
  int c = blockIdx.x, h = blockIdx.y, b = blockIdx.z;
  int bh = b * H_ + h, t = threadIdx.x;
  const size_t rowbase = ((size_t)b * N_ + c * 256) * INNER_ + h * DH_;
  float pr[64];
  #pragma unroll
  for (int q = 0; q < 16; q++){
    float4 p = *(const float4*)&proj[t * DH_ + q * 4];
    pr[4*q] = p.x; pr[4*q+1] = p.y; pr[4*q+2] = p.z; pr[4*q+3] = p.w;
  }
  float mx = -3.4e38f;
  for (int r = 0; r < 256; ++r){
    const float4* kr = (const float4*)(kb + rowbase + (size_t)r * INNER_);
    float d0 = 0, d1 = 0, d2 = 0, d3 = 0;
    #pragma unroll
    for (int q = 0; q < 16; q++){
      float4 kk = kr[q];
      d0 += kk.x * pr[4*q]; d1 += kk.y * pr[4*q+1]; d2 += kk.z * pr[4*q+2]; d3 += kk.w * pr[4*q+3];
    }
    mx = fmaxf(mx, (d0 + d1) + (d2 + d3));
  }
  __shared__ float red[256];
  red[t] = mx; __syncthreads();
  #pragma unroll
  for (int s = 128; s > 0; s >>= 1){ if (t < s) red[t] = fmaxf(red[t], red[t + s]); __syncthreads(); }
  if (t == 0) atomicMax(&stab[bh], fenc(red[0] * DN_));
}

// ---------------- favor-k pass 2: partial ctx and kfsum per ROWS_-row chunk ----------------
__launch_bounds__(256)
__global__ void k_ctx(const float* __restrict__ kb, const __bf16* __restrict__ vb,
                      const float* __restrict__ proj, const unsigned* __restrict__ stab,
                      float* __restrict__ pctx, float* __restrict__ pkf){
  int c = blockIdx.x, h = blockIdx.y, b = blockIdx.z;
  int bh = b * H_ + h, t = threadIdx.x;
  const size_t rowbase = ((size_t)b * N_ + c * ROWS_) * INNER_ + h * DH_;
  float pr[64];
  #pragma unroll
  for (int q = 0; q < 16; q++){
    float4 p = *(const float4*)&proj[t * DH_ + q * 4];
    pr[4*q] = p.x; pr[4*q+1] = p.y; pr[4*q+2] = p.z; pr[4*q+3] = p.w;
  }
  float st = fdec(stab[bh]);
  float cacc[64] = {};
  float ks = 0.f;
  for (int r = 0; r < ROWS_; ++r){
    const float4* kr = (const float4*)(kb + rowbase + (size_t)r * INNER_);
    float d0 = 0, d1 = 0, d2 = 0, d3 = 0;
    float s0 = 0, s1 = 0, s2 = 0, s3 = 0;
    #pragma unroll
    for (int q = 0; q < 16; q++){
      float4 kk = kr[q];
      d0 += kk.x * pr[4*q]; d1 += kk.y * pr[4*q+1]; d2 += kk.z * pr[4*q+2]; d3 += kk.w * pr[4*q+3];
      s0 += kk.x * kk.x; s1 += kk.y * kk.y; s2 += kk.z * kk.z; s3 += kk.w * kk.w;
    }
    float dd = (d0 + d1) + (d2 + d3);
    float diag = 0.5f * DN_ * DN_ * ((s0 + s1) + (s2 + s3));
    float kf = RATIO_ * (__expf(dd * DN_ - diag - st) + KEPS_);
    ks += kf;
    const bf16x8* vr = (const bf16x8*)(vb + rowbase + (size_t)r * INNER_);
    #pragma unroll
    for (int q = 0; q < 8; q++){
      bf16x8 vv = vr[q];
      #pragma unroll
      for (int j = 0; j < 8; j++) cacc[q * 8 + j] += kf * (float)vv[j];
    }
  }
  float* pout = pctx + ((size_t)(c * 16 + bh) * 256 + t) * 64;
  #pragma unroll
  for (int q = 0; q < 16; q++)
    *(float4*)&pout[q * 4] = make_float4(cacc[4*q], cacc[4*q+1], cacc[4*q+2], cacc[4*q+3]);
  pkf[(size_t)(c * 16 + bh) * 256 + t] = ks;
}

__global__ void k_ctxred(const float* __restrict__ pctx, float* __restrict__ ctx){
  int i = blockIdx.x * 256 + threadIdx.x;   // 262144 outputs
  float s = 0.f;
  #pragma unroll
  for (int c = 0; c < CH_; ++c) s += pctx[(size_t)c * 262144 + i];
  ctx[i] = s;
}

__global__ void k_kfred(const float* __restrict__ pkf, float* __restrict__ kfsum){
  int i = blockIdx.x * 256 + threadIdx.x;   // 4096 outputs
  float s = 0.f;
  #pragma unroll
  for (int c = 0; c < CH_; ++c) s += pkf[c * 4096 + i];
  kfsum[i] = s;
}

// ---------------- favor-q fused: qf, denom, o = (qf @ ctx)/denom ----------------
__launch_bounds__(256)
__global__ void k_qo(const float* __restrict__ qb, const float* __restrict__ proj,
                     const float* __restrict__ ctxg, const float* __restrict__ kfsg, __bf16* __restrict__ ob){
  int h = blockIdx.y, b = blockIdx.z, n0 = blockIdx.x * 64;
  int bh = b * H_ + h, t = threadIdx.x;
  __shared__ float qsh[64][68];
  __shared__ float qfsh[64][260];
  __shared__ float ctxsh[128][64];
  __shared__ float kfs[256];
  __shared__ float diag[64], rmax[64], den[64];
  __shared__ float rpart[64][4];
  #pragma unroll
  for (int it = 0; it < 4; ++it){
    int lin = it * 256 + t, r = lin >> 4, q4 = lin & 15;
    *(float4*)&qsh[r][q4 * 4] = *(const float4*)&qb[(size_t)(b * N_ + n0 + r) * INNER_ + h * DH_ + q4 * 4];
  }
  kfs[t] = kfsg[bh * NB_ + t];
  float pr[64];
  #pragma unroll
  for (int q4 = 0; q4 < 16; q4++){
    float4 p = *(const float4*)&proj[t * DH_ + q4 * 4];
    pr[q4 * 4] = p.x; pr[q4 * 4 + 1] = p.y; pr[q4 * 4 + 2] = p.z; pr[q4 * 4 + 3] = p.w;
  }
  __syncthreads();
  if (t < 64){
    float s = 0.f;
    for (int d2 = 0; d2 < 64; d2++){ float qv = qsh[t][d2]; s += qv * qv; }
    diag[t] = 0.5f * DN_ * DN_ * s;
  }
  for (int r = 0; r < 64; r++){
    float d0 = 0, d1 = 0, d2 = 0, d3 = 0;
    #pragma unroll
    for (int q4 = 0; q4 < 16; q4++){
      float4 kk = *(const float4*)&qsh[r][q4 * 4];
      d0 += kk.x * pr[q4*4]; d1 += kk.y * pr[q4*4+1]; d2 += kk.z * pr[q4*4+2]; d3 += kk.w * pr[q4*4+3];
    }
    qfsh[r][t] = ((d0 + d1) + (d2 + d3)) * DN_;
  }
  __syncthreads();
  { int r = t >> 2, seg = t & 3; float mx = -3.4e38f;
    for (int i = 0; i < 64; i++) mx = fmaxf(mx, qfsh[r][seg * 64 + i]);
    rpart[r][seg] = mx; }
  __syncthreads();
  if (t < 64) rmax[t] = fmaxf(fmaxf(rpart[t][0], rpart[t][1]), fmaxf(rpart[t][2], rpart[t][3]));
  __syncthreads();
  for (int r = 0; r < 64; r++){
    qfsh[r][t] = RATIO_ * (__expf(qfsh[r][t] - diag[r] - rmax[r]) + KEPS_);
  }
  __syncthreads();
  { int r = t >> 2, seg = t & 3; float s = 0.f;
    for (int i = 0; i < 64; i++) s += qfsh[r][seg * 64 + i] * kfs[seg * 64 + i];
    rpart[r][seg] = s; }
  __syncthreads();
  if (t < 64) den[t] = rpart[t][0] + rpart[t][1] + rpart[t][2] + rpart[t][3];
  int dq = t & 15, rg = t >> 4, rb = rg * 4;
  float acc[4][4] = {};
  for (int ch = 0; ch < 2; ++ch){
    __syncthreads();
    #pragma unroll
    for (int it = 0; it < 8; ++it){
      int lin = it * 256 + t, m = lin >> 4, q4 = lin & 15;
      *(float4*)&ctxsh[m][q4 * 4] = *(const float4*)&ctxg[(size_t)(bh * NB_ + ch * 128 + m) * DH_ + q4 * 4];
    }
    __syncthreads();
    for (int m = 0; m < 128; m++){
      int mg = ch * 128 + m;
      float4 cv = *(const float4*)&ctxsh[m][dq * 4];
      float q0 = qfsh[rb][mg], q1 = qfsh[rb + 1][mg], q2 = qfsh[rb + 2][mg], q3 = qfsh[rb + 3][mg];
      acc[0][0] += q0 * cv.x; acc[0][1] += q0 * cv.y; acc[0][2] += q0 * cv.z; acc[0][3] += q0 * cv.w;
      acc[1][0] += q1 * cv.x; acc[1][1] += q1 * cv.y; acc[1][2] += q1 * cv.z; acc[1][3] += q1 * cv.w;
      acc[2][0] += q2 * cv.x; acc[2][1] += q2 * cv.y; acc[2][2] += q2 * cv.z; acc[2][3] += q2 * cv.w;
      acc[3][0] += q3 * cv.x; acc[3][1] += q3 * cv.y; acc[3][2] += q3 * cv.z; acc[3][3] += q3 * cv.w;
    }
  }
  #pragma unroll
  for (int rr = 0; rr < 4; rr++){
    float id = 1.f / den[rb + rr];
    __bf16* op = ob + (size_t)(b * N_ + n0 + rb + rr) * INNER_ + h * DH_ + dq * 4;
    op[0] = (__bf16)(acc[rr][0] * id); op[1] = (__bf16)(acc[rr][1] * id);
    op[2] = (__bf16)(acc[rr][2] * id); op[3] = (__bf16)(acc[rr][3] * id);
  }
}

// ---------------- final LN + head ----------------
__launch_bounds__(256)
__global__ void k_final(const float* __restrict__ z, const float* __restrict__ g, const float* __restrict__ bb,
                        const float* __restrict__ ow, const float* __restrict__ obias, float* __restrict__ out){
  int row = blockIdx.x, d = threadIdx.x;
  __shared__ float red[256];
  float v = z[row * DIM_ + d];
  red[d] = v; __syncthreads();
  #pragma unroll
  for (int s = 128; s > 0; s >>= 1){ if (d < s) red[d] += red[d + s]; __syncthreads(); }
  float mean = red[0] * (1.f / DIM_);
  __syncthreads();
  float c = v - mean;
  red[d] = c * c; __syncthreads();
  #pragma unroll
  for (int s = 128; s > 0; s >>= 1){ if (d < s) red[d] += red[d + s]; __syncthreads(); }
  float var = red[0] * (1.f / DIM_);
  __syncthreads();
  float yv = c * rsqrtf(var + LNEPS_) * g[d] + bb[d];
  red[d] = yv * ow[d]; __syncthreads();
  #pragma unroll
  for (int s = 128; s > 0; s >>= 1){ if (d < s) red[d] += red[d + s]; __syncthreads(); }
  if (d == 0) out[row] = red[0] + obias[0];
}

extern "C" void kernel_launch(void* const* d_in, const int* in_sizes, int n_in,
                              void* d_out, int out_size, void* d_ws, size_t ws_size,
                              hipStream_t stream){
  (void)in_sizes; (void)n_in; (void)out_size; (void)ws_size;
  const float* x      = (const float*)d_in[0];
  const float* mlp_w1 = (const float*)d_in[1];
  const float* mlp_b1 = (const float*)d_in[2];
  const float* mlp_w2 = (const float*)d_in[3];
  const float* mlp_b2 = (const float*)d_in[4];
  const float* pos    = (const float*)d_in[5];
  const float* gemb   = (const float*)d_in[6];
  const float* gw     = (const float*)d_in[7];
  const float* gb     = (const float*)d_in[8];
  const float* ew     = (const float*)d_in[9];
  const float* proj   = (const float*)d_in[10];
  const float* ln1g   = (const float*)d_in[11];
  const float* ln1b   = (const float*)d_in[12];
  const float* wq     = (const float*)d_in[13];
  const float* wk     = (const float*)d_in[14];
  const float* wv     = (const float*)d_in[15];
  const float* wo     = (const float*)d_in[16];
  const float* bo     = (const float*)d_in[17];
  const float* ln2g   = (const float*)d_in[18];
  const float* ln2b   = (const float*)d_in[19];
  const float* ffw1   = (const float*)d_in[20];
  const float* ffb1   = (const float*)d_in[21];
  const float* ffw2   = (const float*)d_in[22];
  const float* ffb2   = (const float*)d_in[23];
  const float* nfg    = (const float*)d_in[24];
  const float* nfb    = (const float*)d_in[25];
  const float* ow     = (const float*)d_in[26];
  const float* obias  = (const float*)d_in[27];
  const int*   ei     = (const int*)d_in[28];
  float* out = (float*)d_out;

  // workspace layout (floats). End = 32,854,272 fl = 131.4 MB (< round-1's proven 143.7 MB)
  float* ws = (float*)d_ws;
  float*    deg   = ws;                       // 8,192
  float*    dinv  = ws + 8192;                // 8,192
  unsigned* stab  = (unsigned*)(ws + 16384);  // 256
  float*    kfsum = ws + 16640;               // 4,096
  float*    ctx   = ws + 20736;               // 262,144
  float*    z     = ws + 282880;              // 4,194,304
  float*    qb    = ws + 4477184;             // 8,388,608
  float*    kb    = ws + 12865792;            // 8,388,608
  __bf16*   vb    = (__bf16*)(ws + 21254400); // 8,388,608 elems (4,194,304 fl)
  __bf16*   ybf   = (__bf16*)(ws + 25448704); // 4,194,304 elems (2,097,152 fl)
  __bf16*   wT    = (__bf16*)(ws + 27545856); // 2,097,152 elems (1,048,576 fl)
  float*    pctx  = ws + 28594432;            // 4,194,304 (CH_=16 x 262,144)
  float*    agg   = pctx;                     // 2,097,152 (dead after k_z0; aliases pctx)
  float*    pkf   = ws + 32788736;            // 65,536 -> end 32,854,272 fl
  __bf16*   obf   = vb;                       // alias: v dead after k_ctx
  __bf16*   ffbf  = (__bf16*)qb;              // alias: q dead after k_qo (16.7M bf16 = 33.5 MB fits)

  hipMemsetAsync(deg, 0, N_ * sizeof(float), stream);
  hipMemsetAsync(agg, 0, (size_t)N_ * DIM_ * sizeof(float), stream);

  // weight convert+transpose to bf16 (per layer: wqT,wkT,wvT,woT,ffw1T,ffw2T)
  for (int l = 0; l < 2; ++l){
    __bf16* base = wT + (size_t)l * 1048576;
    k_convT<<<dim3(8, 16), 256, 0, stream>>>(wq + (size_t)l * DIM_ * INNER_, base + 0,      DIM_, INNER_);
    k_convT<<<dim3(8, 16), 256, 0, stream>>>(wk + (size_t)l * DIM_ * INNER_, base + 131072, DIM_, INNER_);
    k_convT<<<dim3(8, 16), 256, 0, stream>>>(wv + (size_t)l * DIM_ * INNER_, base + 262144, DIM_, INNER_);
    k_convT<<<dim3(16, 8), 256, 0, stream>>>(wo + (size_t)l * INNER_ * DIM_, base + 393216, INNER_, DIM_);
    k_convT<<<dim3(8, 32), 256, 0, stream>>>(ffw1 + (size_t)l * DIM_ * FF_,  base + 524288, DIM_, FF_);
    k_convT<<<dim3(32, 8), 256, 0, stream>>>(ffw2 + (size_t)l * FF_ * DIM_,  base + 786432, FF_, DIM_);
  }

  k_deg<<<E_ / 256, 256, 0, stream>>>(ei, ew, deg);
  k_dinv<<<N_ / 256, 256, 0, stream>>>(deg, dinv);
  k_agg<<<E_, 256, 0, stream>>>(ei, ew, dinv, gemb, agg);
  k_z0<<<N_ / 8, 256, 0, stream>>>(x, mlp_w1, mlp_b1, mlp_w2, mlp_b2, pos, agg, gw, gb, z);

  for (int l = 0; l < 2; ++l){
    __bf16* wqT = wT + (size_t)l * 1048576;
    __bf16* wkT = wqT + 131072;
    __bf16* wvT = wqT + 262144;
    __bf16* woT = wqT + 393216;
    __bf16* f1T = wqT + 524288;
    __bf16* f2T = wqT + 786432;
    hipMemsetAsync(stab, 0, 16 * sizeof(unsigned), stream);
    k_ln<<<B_ * N_, 256, 0, stream>>>(z, ln1g + l * DIM_, ln1b + l * DIM_, ybf);
    k_gemm_bt<0><<<dim3(128, 4), 256, 0, stream>>>(ybf, wqT, nullptr, qb, nullptr, B_ * N_, INNER_, DIM_);
    k_gemm_bt<0><<<dim3(128, 4), 256, 0, stream>>>(ybf, wkT, nullptr, kb, nullptr, B_ * N_, INNER_, DIM_);
    k_gemm_bt<3><<<dim3(128, 4), 256, 0, stream>>>(ybf, wvT, nullptr, nullptr, vb, B_ * N_, INNER_, DIM_);
    k_stab<<<dim3(32, H_, B_), 256, 0, stream>>>(kb, proj, stab);
    k_ctx<<<dim3(CH_, H_, B_), 256, 0, stream>>>(kb, vb, proj, stab, pctx, pkf);
    k_ctxred<<<1024, 256, 0, stream>>>(pctx, ctx);
    k_kfred<<<16, 256, 0, stream>>>(pkf, kfsum);
    k_qo<<<dim3(N_ / 64, H_, B_), 256, 0, stream>>>(qb, proj, ctx, kfsum, obf);
    k_gemm_bt<1><<<dim3(128, 2), 256, 0, stream>>>(obf, woT, bo + l * DIM_, z, nullptr, B_ * N_, DIM_, INNER_);
    k_ln<<<B_ * N_, 256, 0, stream>>>(z, ln2g + l * DIM_, ln2b + l * DIM_, ybf);
    k_gemm_bt<2><<<dim3(128, 8), 256, 0, stream>>>(ybf, f1T, ffb1 + l * FF_, nullptr, ffbf, B_ * N_, FF_, DIM_);
    k_gemm_bt<1><<<dim3(128, 2), 256, 0, stream>>>(ffbf, f2T, ffb2 + l * DIM_, z, nullptr, B_ * N_, DIM_, FF_);
  }
  k_final<<<B_ * N_, 256, 0, stream>>>(z, nfg, nfb, ow, obias, out);
}

// Round 9
// 2973.651 us; speedup vs baseline: 1.4718x; 1.3147x over previous
//
#include <hip/hip_runtime.h>
#include <cmath>

#define HD __device__ __forceinline__

constexpr int B_ = 2, N_ = 8192, DIM_ = 256, H_ = 8, DH_ = 64, INNER_ = 512, NB_ = 256, FF_ = 1024, E_ = 131072;
constexpr int CH_ = 32, ROWS_ = N_ / CH_;   // favor-k chunking: 32 chunks x 256 rows
constexpr float LNEPS_ = 1e-5f, KEPS_ = 1e-4f;
constexpr float DN_ = 0.35355339059327373f;   // 64^-0.25
constexpr float RATIO_ = 0.0625f;             // 256^-0.5

typedef __attribute__((ext_vector_type(8))) __bf16 bf16x8;
typedef __attribute__((ext_vector_type(4))) float f32x4;

HD unsigned fenc(float f){ unsigned b = __float_as_uint(f); return (b & 0x80000000u) ? ~b : (b | 0x80000000u); }
HD float fdec(unsigned u){ return (u & 0x80000000u) ? __uint_as_float(u & 0x7FFFFFFFu) : __uint_as_float(~u); }
HD float gelu_tanh(float x){
  float t = tanhf(0.7978845608028654f * (x + 0.044715f * x * x * x));
  return 0.5f * x * (1.f + t);
}
HD void gload16(const void* g, void* l){
  __builtin_amdgcn_global_load_lds((const __attribute__((address_space(1))) void*)g,
                                   (__attribute__((address_space(3))) void*)l, 16, 0, 0);
}

// ---------------- GNN ----------------
__global__ void k_deg(const int* __restrict__ ei, const float* __restrict__ ew, float* __restrict__ deg){
  int e = blockIdx.x * 256 + threadIdx.x;
  if (e < E_) atomicAdd(&deg[ei[E_ + e]], ew[e]);
}

__global__ void k_dinv(const float* __restrict__ deg, float* __restrict__ dinv){
  int i = blockIdx.x * 256 + threadIdx.x;
  if (i < N_){ float d = deg[i]; dinv[i] = d > 0.f ? rsqrtf(fmaxf(d, 1e-12f)) : 0.f; }
}

__global__ void k_agg(const int* __restrict__ ei, const float* __restrict__ ew, const float* __restrict__ dinv,
                      const float* __restrict__ gemb, float* __restrict__ agg){
  int e = blockIdx.x; int d = threadIdx.x;
  int r = ei[e], c = ei[E_ + e];
  float en = dinv[r] * ew[e] * dinv[c];
  atomicAdd(&agg[c * DIM_ + d], gemb[r * DIM_ + d] * en);
}

// ---------------- z0 = emb + pos + go ----------------
__launch_bounds__(256)
__global__ void k_z0(const float* __restrict__ x, const float* __restrict__ w1, const float* __restrict__ b1,
                     const float* __restrict__ w2, const float* __restrict__ b2,
                     const float* __restrict__ pos, const float* __restrict__ agg,
                     const float* __restrict__ gw, const float* __restrict__ gb, float* __restrict__ z){
  __shared__ float hsh[2][8][DIM_];
  __shared__ float ash[8][DIM_];
  int n0 = blockIdx.x * 8; int d = threadIdx.x;
  #pragma unroll
  for (int r = 0; r < 8; r++){
    ash[r][d] = agg[(n0 + r) * DIM_ + d];
    hsh[0][r][d] = fmaxf(x[n0 + r] * w1[d] + b1[d], 0.f);
    hsh[1][r][d] = fmaxf(x[N_ + n0 + r] * w1[d] + b1[d], 0.f);
  }
  __syncthreads();
  float go[8] = {}, e0[8] = {}, e1[8] = {};
  for (int k = 0; k < DIM_; k++){
    float wgk = gw[k * DIM_ + d], w2k = w2[k * DIM_ + d];
    #pragma unroll
    for (int r = 0; r < 8; r++){
      go[r] += ash[r][k] * wgk;
      e0[r] += hsh[0][r][k] * w2k;
      e1[r] += hsh[1][r][k] * w2k;
    }
  }
  #pragma unroll
  for (int r = 0; r < 8; r++){
    float base = go[r] + gb[d] + pos[(n0 + r) * DIM_ + d] + b2[d];
    z[(n0 + r) * DIM_ + d]      = e0[r] + base;
    z[(N_ + n0 + r) * DIM_ + d] = e1[r] + base;
  }
}

// ---------------- LayerNorm (bf16 out) ----------------
__launch_bounds__(256)
__global__ void k_ln(const float* __restrict__ z, const float* __restrict__ g, const float* __restrict__ bb,
                     __bf16* __restrict__ y){
  int row = blockIdx.x, d = threadIdx.x;
  __shared__ float red[256];
  float v = z[row * DIM_ + d];
  red[d] = v; __syncthreads();
  #pragma unroll
  for (int s = 128; s > 0; s >>= 1){ if (d < s) red[d] += red[d + s]; __syncthreads(); }
  float mean = red[0] * (1.f / DIM_);
  __syncthreads();
  float c = v - mean;
  red[d] = c * c; __syncthreads();
  #pragma unroll
  for (int s = 128; s > 0; s >>= 1){ if (d < s) red[d] += red[d + s]; __syncthreads(); }
  float var = red[0] * (1.f / DIM_);
  y[row * DIM_ + d] = (__bf16)(c * rsqrtf(var + LNEPS_) * g[d] + bb[d]);
}

// ---------------- weight transpose+convert: src[K][N] f32 -> dst[N][K] bf16 ----------------
__launch_bounds__(256)
__global__ void k_convT(const float* __restrict__ src, __bf16* __restrict__ dst, int K, int N){
  __shared__ float tile[32][33];
  int kb0 = blockIdx.x * 32, nb0 = blockIdx.y * 32;
  int tx = threadIdx.x & 31, ty = threadIdx.x >> 5;
  #pragma unroll
  for (int i = 0; i < 32; i += 8)
    tile[ty + i][tx] = src[(size_t)(kb0 + ty + i) * N + nb0 + tx];
  __syncthreads();
  #pragma unroll
  for (int i = 0; i < 32; i += 8)
    dst[(size_t)(nb0 + ty + i) * K + kb0 + tx] = (__bf16)tile[tx][ty + i];
}

// ---------------- bf16 MFMA GEMM: C[M][N] = A[M][K] @ BT[N][K]^T ----------------
// EPI: 0 = C f32 = AB (+bias); 1 = C f32 += AB + bias (residual);
//      2 = Cb bf16 = gelu(AB + bias);      3 = Cb bf16 = AB
template<int EPI>
__launch_bounds__(256)
__global__ void k_gemm_bt(const __bf16* __restrict__ A, const __bf16* __restrict__ BT,
                          const float* __restrict__ bias, float* __restrict__ C,
                          __bf16* __restrict__ Cb, int M, int Nn, int K){
  __shared__ __align__(16) __bf16 As[128 * 64];
  __shared__ __align__(16) __bf16 Bs[128 * 64];
  int t = threadIdx.x;
  int w = t >> 6, l = t & 63;
  int m0 = blockIdx.x * 128, n0 = blockIdx.y * 128;
  int wm = w >> 1, wn = w & 1;
  int lr = l & 15, lk = (l >> 4) * 8;
  f32x4 acc[4][4];
  #pragma unroll
  for (int i = 0; i < 4; ++i)
    #pragma unroll
    for (int j = 0; j < 4; ++j) acc[i][j] = 0.f;

  for (int kt = 0; kt < K; kt += 64){
    #pragma unroll
    for (int c = 0; c < 4; ++c){
      int chunk = c * 256 + w * 64 + l;
      int row = chunk >> 3, off = (chunk & 7) * 8;
      int ldsbase = (c * 256 + w * 64) * 8;
      gload16(A + (size_t)(m0 + row) * K + kt + off, (void*)(As + ldsbase));
      gload16(BT + (size_t)(n0 + row) * K + kt + off, (void*)(Bs + ldsbase));
    }
    asm volatile("s_waitcnt vmcnt(0)" ::: "memory");
    __syncthreads();
    #pragma unroll
    for (int kk = 0; kk < 2; ++kk){
      bf16x8 af[4], bfr[4];
      #pragma unroll
      for (int i = 0; i < 4; ++i)
        af[i] = *(const bf16x8*)&As[(wm * 64 + i * 16 + lr) * 64 + kk * 32 + lk];
      #pragma unroll
      for (int j = 0; j < 4; ++j)
        bfr[j] = *(const bf16x8*)&Bs[(wn * 64 + j * 16 + lr) * 64 + kk * 32 + lk];
      #pragma unroll
      for (int i = 0; i < 4; ++i)
        #pragma unroll
        for (int j = 0; j < 4; ++j)
          acc[i][j] = __builtin_amdgcn_mfma_f32_16x16x32_bf16(af[i], bfr[j], acc[i][j], 0, 0, 0);
    }
    __syncthreads();
  }
  int cr = (l >> 4) * 4;
  #pragma unroll
  for (int i = 0; i < 4; ++i){
    #pragma unroll
    for (int j = 0; j < 4; ++j){
      int row = m0 + wm * 64 + i * 16 + cr;
      int col = n0 + wn * 64 + j * 16 + lr;
      float bv = bias ? bias[col] : 0.f;
      #pragma unroll
      for (int r = 0; r < 4; ++r){
        float v = acc[i][j][r] + bv;
        if (EPI == 0) C[(size_t)(row + r) * Nn + col] = v;
        if (EPI == 1) C[(size_t)(row + r) * Nn + col] += v;
        if (EPI == 2) Cb[(size_t)(row + r) * Nn + col] = (__bf16)gelu_tanh(v);
        if (EPI == 3) Cb[(size_t)(row + r) * Nn + col] = (__bf16)v;
      }
    }
  }
}

// ---------------- favor-k pass 1: stab_k[b,h] = max over (n,m) of dd*DN ----------------
// launch_bounds(256,1): lift VGPR cap so pr[64] stays in registers (no spill).
__launch_bounds__(256, 1)
__global__ void k_stab(const float* __restrict__ kb, const float* __restrict__ proj, unsigned* __restrict__ stab){
  int c = blockIdx.x, h = blockIdx.y, b = blockIdx.z;
  int bh = b * H_ + h, t = threadIdx.x;
  const size_t rowbase = ((size_t)b * N_ + c * ROWS_) * INNER_ + h * DH_;
  float pr[64];
  #pragma unroll
  for (int q = 0; q < 16; q++){
    float4 p = *(const float4*)&proj[t * DH_ + q * 4];
    pr[4*q] = p.x; pr[4*q+1] = p.y; pr[4*q+2] = p.z; pr[4*q+3] = p.w;
  }
  float mx = -3.4e38f;
  for (int r = 0; r < ROWS_; ++r){
    const float4* kr = (const float4*)(kb + rowbase + (size_t)r * INNER_);
    float d0 = 0, d1 = 0, d2 = 0, d3 = 0;
    #pragma unroll
    for (int q = 0; q < 16; q++){
      float4 kk = kr[q];
      d0 += kk.x * pr[4*q]; d1 += kk.y * pr[4*q+1]; d2 += kk.z * pr[4*q+2]; d3 += kk.w * pr[4*q+3];
    }
    mx = fmaxf(mx, (d0 + d1) + (d2 + d3));
  }
  __shared__ float red[256];
  red[t] = mx; __syncthreads();
  #pragma unroll
  for (int s = 128; s > 0; s >>= 1){ if (t < s) red[t] = fmaxf(red[t], red[t + s]); __syncthreads(); }
  if (t == 0) atomicMax(&stab[bh], fenc(red[0] * DN_));
}

// ---------------- favor-k pass 2: f32 partial ctx and kfsum per ROWS_-row chunk ----------------
// launch_bounds(256,1): pr[64]+cacc[64] live in registers (~160 VGPR, zero scratch).
__launch_bounds__(256, 1)
__global__ void k_ctx(const float* __restrict__ kb, const __bf16* __restrict__ vb,
                      const float* __restrict__ proj, const unsigned* __restrict__ stab,
                      float* __restrict__ pctx, float* __restrict__ pkf){
  int c = blockIdx.x, h = blockIdx.y, b = blockIdx.z;
  int bh = b * H_ + h, t = threadIdx.x;
  const size_t rowbase = ((size_t)b * N_ + c * ROWS_) * INNER_ + h * DH_;
  float pr[64];
  #pragma unroll
  for (int q = 0; q < 16; q++){
    float4 p = *(const float4*)&proj[t * DH_ + q * 4];
    pr[4*q] = p.x; pr[4*q+1] = p.y; pr[4*q+2] = p.z; pr[4*q+3] = p.w;
  }
  float st = fdec(stab[bh]);
  float cacc[64] = {};
  float ks = 0.f;
  for (int r = 0; r < ROWS_; ++r){
    const float4* kr = (const float4*)(kb + rowbase + (size_t)r * INNER_);
    float d0 = 0, d1 = 0, d2 = 0, d3 = 0;
    float s0 = 0, s1 = 0, s2 = 0, s3 = 0;
    #pragma unroll
    for (int q = 0; q < 16; q++){
      float4 kk = kr[q];
      d0 += kk.x * pr[4*q]; d1 += kk.y * pr[4*q+1]; d2 += kk.z * pr[4*q+2]; d3 += kk.w * pr[4*q+3];
      s0 += kk.x * kk.x; s1 += kk.y * kk.y; s2 += kk.z * kk.z; s3 += kk.w * kk.w;
    }
    float dd = (d0 + d1) + (d2 + d3);
    float diag = 0.5f * DN_ * DN_ * ((s0 + s1) + (s2 + s3));
    float kf = RATIO_ * (__expf(dd * DN_ - diag - st) + KEPS_);
    ks += kf;
    const bf16x8* vr = (const bf16x8*)(vb + rowbase + (size_t)r * INNER_);
    #pragma unroll
    for (int q = 0; q < 8; q++){
      bf16x8 vv = vr[q];
      #pragma unroll
      for (int j = 0; j < 8; j++) cacc[q * 8 + j] += kf * (float)vv[j];
    }
  }
  float* pout = pctx + ((size_t)(c * 16 + bh) * 256 + t) * 64;
  #pragma unroll
  for (int q = 0; q < 16; q++)
    *(float4*)&pout[q * 4] = make_float4(cacc[4*q], cacc[4*q+1], cacc[4*q+2], cacc[4*q+3]);
  pkf[(size_t)(c * 16 + bh) * 256 + t] = ks;
}

__global__ void k_ctxred(const float* __restrict__ pctx, float* __restrict__ ctx){
  int i = blockIdx.x * 256 + threadIdx.x;   // 262144 outputs
  float s = 0.f;
  #pragma unroll
  for (int c = 0; c < CH_; ++c) s += pctx[(size_t)c * 262144 + i];
  ctx[i] = s;
}

__global__ void k_kfred(const float* __restrict__ pkf, float* __restrict__ kfsum){
  int i = blockIdx.x * 256 + threadIdx.x;   // 4096 outputs
  float s = 0.f;
  #pragma unroll
  for (int c = 0; c < CH_; ++c) s += pkf[c * 4096 + i];
  kfsum[i] = s;
}

// ---------------- favor-q fused: qf, denom, o = (qf @ ctx)/denom ----------------
__launch_bounds__(256)
__global__ void k_qo(const float* __restrict__ qb, const float* __restrict__ proj,
                     const float* __restrict__ ctxg, const float* __restrict__ kfsg, __bf16* __restrict__ ob){
  int h = blockIdx.y, b = blockIdx.z, n0 = blockIdx.x * 64;
  int bh = b * H_ + h, t = threadIdx.x;
  __shared__ float qsh[64][68];
  __shared__ float qfsh[64][260];
  __shared__ float ctxsh[128][64];
  __shared__ float kfs[256];
  __shared__ float diag[64], rmax[64], den[64];
  __shared__ float rpart[64][4];
  #pragma unroll
  for (int it = 0; it < 4; ++it){
    int lin = it * 256 + t, r = lin >> 4, q4 = lin & 15;
    *(float4*)&qsh[r][q4 * 4] = *(const float4*)&qb[(size_t)(b * N_ + n0 + r) * INNER_ + h * DH_ + q4 * 4];
  }
  kfs[t] = kfsg[bh * NB_ + t];
  float pr[64];
  #pragma unroll
  for (int q4 = 0; q4 < 16; q4++){
    float4 p = *(const float4*)&proj[t * DH_ + q4 * 4];
    pr[q4 * 4] = p.x; pr[q4 * 4 + 1] = p.y; pr[q4 * 4 + 2] = p.z; pr[q4 * 4 + 3] = p.w;
  }
  __syncthreads();
  if (t < 64){
    float s = 0.f;
    for (int d2 = 0; d2 < 64; d2++){ float qv = qsh[t][d2]; s += qv * qv; }
    diag[t] = 0.5f * DN_ * DN_ * s;
  }
  for (int r = 0; r < 64; r++){
    float d0 = 0, d1 = 0, d2 = 0, d3 = 0;
    #pragma unroll
    for (int q4 = 0; q4 < 16; q4++){
      float4 kk = *(const float4*)&qsh[r][q4 * 4];
      d0 += kk.x * pr[q4*4]; d1 += kk.y * pr[q4*4+1]; d2 += kk.z * pr[q4*4+2]; d3 += kk.w * pr[q4*4+3];
    }
    qfsh[r][t] = ((d0 + d1) + (d2 + d3)) * DN_;
  }
  __syncthreads();
  { int r = t >> 2, seg = t & 3; float mx = -3.4e38f;
    for (int i = 0; i < 64; i++) mx = fmaxf(mx, qfsh[r][seg * 64 + i]);
    rpart[r][seg] = mx; }
  __syncthreads();
  if (t < 64) rmax[t] = fmaxf(fmaxf(rpart[t][0], rpart[t][1]), fmaxf(rpart[t][2], rpart[t][3]));
  __syncthreads();
  for (int r = 0; r < 64; r++){
    qfsh[r][t] = RATIO_ * (__expf(qfsh[r][t] - diag[r] - rmax[r]) + KEPS_);
  }
  __syncthreads();
  { int r = t >> 2, seg = t & 3; float s = 0.f;
    for (int i = 0; i < 64; i++) s += qfsh[r][seg * 64 + i] * kfs[seg * 64 + i];
    rpart[r][seg] = s; }
  __syncthreads();
  if (t < 64) den[t] = rpart[t][0] + rpart[t][1] + rpart[t][2] + rpart[t][3];
  int dq = t & 15, rg = t >> 4, rb = rg * 4;
  float acc[4][4] = {};
  for (int ch = 0; ch < 2; ++ch){
    __syncthreads();
    #pragma unroll
    for (int it = 0; it < 8; ++it){
      int lin = it * 256 + t, m = lin >> 4, q4 = lin & 15;
      *(float4*)&ctxsh[m][q4 * 4] = *(const float4*)&ctxg[(size_t)(bh * NB_ + ch * 128 + m) * DH_ + q4 * 4];
    }
    __syncthreads();
    for (int m = 0; m < 128; m++){
      int mg = ch * 128 + m;
      float4 cv = *(const float4*)&ctxsh[m][dq * 4];
      float q0 = qfsh[rb][mg], q1 = qfsh[rb + 1][mg], q2 = qfsh[rb + 2][mg], q3 = qfsh[rb + 3][mg];
      acc[0][0] += q0 * cv.x; acc[0][1] += q0 * cv.y; acc[0][2] += q0 * cv.z; acc[0][3] += q0 * cv.w;
      acc[1][0] += q1 * cv.x; acc[1][1] += q1 * cv.y; acc[1][2] += q1 * cv.z; acc[1][3] += q1 * cv.w;
      acc[2][0] += q2 * cv.x; acc[2][1] += q2 * cv.y; acc[2][2] += q2 * cv.z; acc[2][3] += q2 * cv.w;
      acc[3][0] += q3 * cv.x; acc[3][1] += q3 * cv.y; acc[3][2] += q3 * cv.z; acc[3][3] += q3 * cv.w;
    }
  }
  #pragma unroll
  for (int rr = 0; rr < 4; rr++){
    float id = 1.f / den[rb + rr];
    __bf16* op = ob + (size_t)(b * N_ + n0 + rb + rr) * INNER_ + h * DH_ + dq * 4;
    op[0] = (__bf16)(acc[rr][0] * id); op[1] = (__bf16)(acc[rr][1] * id);
    op[2] = (__bf16)(acc[rr][2] * id); op[3] = (__bf16)(acc[rr][3] * id);
  }
}

// ---------------- final LN + head ----------------
__launch_bounds__(256)
__global__ void k_final(const float* __restrict__ z, const float* __restrict__ g, const float* __restrict__ bb,
                        const float* __restrict__ ow, const float* __restrict__ obias, float* __restrict__ out){
  int row = blockIdx.x, d = threadIdx.x;
  __shared__ float red[256];
  float v = z[row * DIM_ + d];
  red[d] = v; __syncthreads();
  #pragma unroll
  for (int s = 128; s > 0; s >>= 1){ if (d < s) red[d] += red[d + s]; __syncthreads(); }
  float mean = red[0] * (1.f / DIM_);
  __syncthreads();
  float c = v - mean;
  red[d] = c * c; __syncthreads();
  #pragma unroll
  for (int s = 128; s > 0; s >>= 1){ if (d < s) red[d] += red[d + s]; __syncthreads(); }
  float var = red[0] * (1.f / DIM_);
  __syncthreads();
  float yv = c * rsqrtf(var + LNEPS_) * g[d] + bb[d];
  red[d] = yv * ow[d]; __syncthreads();
  #pragma unroll
  for (int s = 128; s > 0; s >>= 1){ if (d < s) red[d] += red[d + s]; __syncthreads(); }
  if (d == 0) out[row] = red[0] + obias[0];
}

extern "C" void kernel_launch(void* const* d_in, const int* in_sizes, int n_in,
                              void* d_out, int out_size, void* d_ws, size_t ws_size,
                              hipStream_t stream){
  (void)in_sizes; (void)n_in; (void)out_size; (void)ws_size;
  const float* x      = (const float*)d_in[0];
  const float* mlp_w1 = (const float*)d_in[1];
  const float* mlp_b1 = (const float*)d_in[2];
  const float* mlp_w2 = (const float*)d_in[3];
  const float* mlp_b2 = (const float*)d_in[4];
  const float* pos    = (const float*)d_in[5];
  const float* gemb   = (const float*)d_in[6];
  const float* gw     = (const float*)d_in[7];
  const float* gb     = (const float*)d_in[8];
  const float* ew     = (const float*)d_in[9];
  const float* proj   = (const float*)d_in[10];
  const float* ln1g   = (const float*)d_in[11];
  const float* ln1b   = (const float*)d_in[12];
  const float* wq     = (const float*)d_in[13];
  const float* wk     = (const float*)d_in[14];
  const float* wv     = (const float*)d_in[15];
  const float* wo     = (const float*)d_in[16];
  const float* bo     = (const float*)d_in[17];
  const float* ln2g   = (const float*)d_in[18];
  const float* ln2b   = (const float*)d_in[19];
  const float* ffw1   = (const float*)d_in[20];
  const float* ffb1   = (const float*)d_in[21];
  const float* ffw2   = (const float*)d_in[22];
  const float* ffb2   = (const float*)d_in[23];
  const float* nfg    = (const float*)d_in[24];
  const float* nfb    = (const float*)d_in[25];
  const float* ow     = (const float*)d_in[26];
  const float* obias  = (const float*)d_in[27];
  const int*   ei     = (const int*)d_in[28];
  float* out = (float*)d_out;

  // workspace layout (floats). End = 37,114,112 fl = 148.46 MB (round-1-proven footprint)
  float* ws = (float*)d_ws;
  float*    deg   = ws;                       // 8,192
  float*    dinv  = ws + 8192;                // 8,192
  unsigned* stab  = (unsigned*)(ws + 16384);  // 256
  float*    kfsum = ws + 16640;               // 4,096
  float*    ctx   = ws + 20736;               // 262,144
  float*    z     = ws + 282880;              // 4,194,304
  float*    qb    = ws + 4477184;             // 8,388,608
  float*    kb    = ws + 12865792;            // 8,388,608
  __bf16*   vb    = (__bf16*)(ws + 21254400); // 8,388,608 elems (4,194,304 fl)
  __bf16*   ybf   = (__bf16*)(ws + 25448704); // 4,194,304 elems (2,097,152 fl)
  __bf16*   wT    = (__bf16*)(ws + 27545856); // 2,097,152 elems (1,048,576 fl)
  float*    pctx  = ws + 28594432;            // 8,388,608 (CH_=32 x 262,144)
  float*    agg   = pctx;                     // 2,097,152 (dead after k_z0; aliases pctx)
  float*    pkf   = ws + 36983040;            // 131,072 -> end 37,114,112 fl
  __bf16*   obf   = vb;                       // alias: v dead after k_ctx
  __bf16*   ffbf  = (__bf16*)qb;              // alias: q dead after k_qo (16.7M bf16 fits)

  hipMemsetAsync(deg, 0, N_ * sizeof(float), stream);
  hipMemsetAsync(agg, 0, (size_t)N_ * DIM_ * sizeof(float), stream);

  // weight convert+transpose to bf16 (per layer: wqT,wkT,wvT,woT,ffw1T,ffw2T)
  for (int l = 0; l < 2; ++l){
    __bf16* base = wT + (size_t)l * 1048576;
    k_convT<<<dim3(8, 16), 256, 0, stream>>>(wq + (size_t)l * DIM_ * INNER_, base + 0,      DIM_, INNER_);
    k_convT<<<dim3(8, 16), 256, 0, stream>>>(wk + (size_t)l * DIM_ * INNER_, base + 131072, DIM_, INNER_);
    k_convT<<<dim3(8, 16), 256, 0, stream>>>(wv + (size_t)l * DIM_ * INNER_, base + 262144, DIM_, INNER_);
    k_convT<<<dim3(16, 8), 256, 0, stream>>>(wo + (size_t)l * INNER_ * DIM_, base + 393216, INNER_, DIM_);
    k_convT<<<dim3(8, 32), 256, 0, stream>>>(ffw1 + (size_t)l * DIM_ * FF_,  base + 524288, DIM_, FF_);
    k_convT<<<dim3(32, 8), 256, 0, stream>>>(ffw2 + (size_t)l * FF_ * DIM_,  base + 786432, FF_, DIM_);
  }

  k_deg<<<E_ / 256, 256, 0, stream>>>(ei, ew, deg);
  k_dinv<<<N_ / 256, 256, 0, stream>>>(deg, dinv);
  k_agg<<<E_, 256, 0, stream>>>(ei, ew, dinv, gemb, agg);
  k_z0<<<N_ / 8, 256, 0, stream>>>(x, mlp_w1, mlp_b1, mlp_w2, mlp_b2, pos, agg, gw, gb, z);

  for (int l = 0; l < 2; ++l){
    __bf16* wqT = wT + (size_t)l * 1048576;
    __bf16* wkT = wqT + 131072;
    __bf16* wvT = wqT + 262144;
    __bf16* woT = wqT + 393216;
    __bf16* f1T = wqT + 524288;
    __bf16* f2T = wqT + 786432;
    hipMemsetAsync(stab, 0, 16 * sizeof(unsigned), stream);
    k_ln<<<B_ * N_, 256, 0, stream>>>(z, ln1g + l * DIM_, ln1b + l * DIM_, ybf);
    k_gemm_bt<0><<<dim3(128, 4), 256, 0, stream>>>(ybf, wqT, nullptr, qb, nullptr, B_ * N_, INNER_, DIM_);
    k_gemm_bt<0><<<dim3(128, 4), 256, 0, stream>>>(ybf, wkT, nullptr, kb, nullptr, B_ * N_, INNER_, DIM_);
    k_gemm_bt<3><<<dim3(128, 4), 256, 0, stream>>>(ybf, wvT, nullptr, nullptr, vb, B_ * N_, INNER_, DIM_);
    k_stab<<<dim3(CH_, H_, B_), 256, 0, stream>>>(kb, proj, stab);
    k_ctx<<<dim3(CH_, H_, B_), 256, 0, stream>>>(kb, vb, proj, stab, pctx, pkf);
    k_ctxred<<<1024, 256, 0, stream>>>(pctx, ctx);
    k_kfred<<<16, 256, 0, stream>>>(pkf, kfsum);
    k_qo<<<dim3(N_ / 64, H_, B_), 256, 0, stream>>>(qb, proj, ctx, kfsum, obf);
    k_gemm_bt<1><<<dim3(128, 2), 256, 0, stream>>>(obf, woT, bo + l * DIM_, z, nullptr, B_ * N_, DIM_, INNER_);
    k_ln<<<B_ * N_, 256, 0, stream>>>(z, ln2g + l * DIM_, ln2b + l * DIM_, ybf);
    k_gemm_bt<2><<<dim3(128, 8), 256, 0, stream>>>(ybf, f1T, ffb1 + l * FF_, nullptr, ffbf, B_ * N_, FF_, DIM_);
    k_gemm_bt<1><<<dim3(128, 2), 256, 0, stream>>>(ffbf, f2T, ffb2 + l * DIM_, z, nullptr, B_ * N_, DIM_, FF_);
  }
  k_final<<<B_ * N_, 256, 0, stream>>>(z, nfg, nfb, ow, obias, out);
}

// Round 10
// 1928.350 us; speedup vs baseline: 2.2697x; 1.5421x over previous
//
#include <hip/hip_runtime.h>
#include <cmath>

#define HD __device__ __forceinline__

constexpr int B_ = 2, N_ = 8192, DIM_ = 256, H_ = 8, DH_ = 64, INNER_ = 512, NB_ = 256, FF_ = 1024, E_ = 131072;
constexpr int CH_ = 32, ROWS_ = N_ / CH_;   // favor-k chunking: 32 chunks x 256 rows
constexpr float LNEPS_ = 1e-5f, KEPS_ = 1e-4f;
constexpr float DN_ = 0.35355339059327373f;   // 64^-0.25
constexpr float RATIO_ = 0.0625f;             // 256^-0.5

typedef __attribute__((ext_vector_type(8))) __bf16 bf16x8;
typedef __attribute__((ext_vector_type(4))) float f32x4;

HD float gelu_tanh(float x){
  float t = tanhf(0.7978845608028654f * (x + 0.044715f * x * x * x));
  return 0.5f * x * (1.f + t);
}
HD void gload16(const void* g, void* l){
  __builtin_amdgcn_global_load_lds((const __attribute__((address_space(1))) void*)g,
                                   (__attribute__((address_space(3))) void*)l, 16, 0, 0);
}

// ---------------- GNN ----------------
__global__ void k_deg(const int* __restrict__ ei, const float* __restrict__ ew, float* __restrict__ deg){
  int e = blockIdx.x * 256 + threadIdx.x;
  if (e < E_) atomicAdd(&deg[ei[E_ + e]], ew[e]);
}

__global__ void k_dinv(const float* __restrict__ deg, float* __restrict__ dinv){
  int i = blockIdx.x * 256 + threadIdx.x;
  if (i < N_){ float d = deg[i]; dinv[i] = d > 0.f ? rsqrtf(fmaxf(d, 1e-12f)) : 0.f; }
}

__global__ void k_agg(const int* __restrict__ ei, const float* __restrict__ ew, const float* __restrict__ dinv,
                      const float* __restrict__ gemb, float* __restrict__ agg){
  int e = blockIdx.x; int d = threadIdx.x;
  int r = ei[e], c = ei[E_ + e];
  float en = dinv[r] * ew[e] * dinv[c];
  atomicAdd(&agg[c * DIM_ + d], gemb[r * DIM_ + d] * en);
}

// ---------------- z0 = emb + pos + go ----------------
__launch_bounds__(256)
__global__ void k_z0(const float* __restrict__ x, const float* __restrict__ w1, const float* __restrict__ b1,
                     const float* __restrict__ w2, const float* __restrict__ b2,
                     const float* __restrict__ pos, const float* __restrict__ agg,
                     const float* __restrict__ gw, const float* __restrict__ gb, float* __restrict__ z){
  __shared__ float hsh[2][8][DIM_];
  __shared__ float ash[8][DIM_];
  int n0 = blockIdx.x * 8; int d = threadIdx.x;
  #pragma unroll
  for (int r = 0; r < 8; r++){
    ash[r][d] = agg[(n0 + r) * DIM_ + d];
    hsh[0][r][d] = fmaxf(x[n0 + r] * w1[d] + b1[d], 0.f);
    hsh[1][r][d] = fmaxf(x[N_ + n0 + r] * w1[d] + b1[d], 0.f);
  }
  __syncthreads();
  float go[8] = {}, e0[8] = {}, e1[8] = {};
  for (int k = 0; k < DIM_; k++){
    float wgk = gw[k * DIM_ + d], w2k = w2[k * DIM_ + d];
    #pragma unroll
    for (int r = 0; r < 8; r++){
      go[r] += ash[r][k] * wgk;
      e0[r] += hsh[0][r][k] * w2k;
      e1[r] += hsh[1][r][k] * w2k;
    }
  }
  #pragma unroll
  for (int r = 0; r < 8; r++){
    float base = go[r] + gb[d] + pos[(n0 + r) * DIM_ + d] + b2[d];
    z[(n0 + r) * DIM_ + d]      = e0[r] + base;
    z[(N_ + n0 + r) * DIM_ + d] = e1[r] + base;
  }
}

// ---------------- LayerNorm (bf16 out) ----------------
__launch_bounds__(256)
__global__ void k_ln(const float* __restrict__ z, const float* __restrict__ g, const float* __restrict__ bb,
                     __bf16* __restrict__ y){
  int row = blockIdx.x, d = threadIdx.x;
  __shared__ float red[256];
  float v = z[row * DIM_ + d];
  red[d] = v; __syncthreads();
  #pragma unroll
  for (int s = 128; s > 0; s >>= 1){ if (d < s) red[d] += red[d + s]; __syncthreads(); }
  float mean = red[0] * (1.f / DIM_);
  __syncthreads();
  float c = v - mean;
  red[d] = c * c; __syncthreads();
  #pragma unroll
  for (int s = 128; s > 0; s >>= 1){ if (d < s) red[d] += red[d + s]; __syncthreads(); }
  float var = red[0] * (1.f / DIM_);
  y[row * DIM_ + d] = (__bf16)(c * rsqrtf(var + LNEPS_) * g[d] + bb[d]);
}

// ---------------- weight transpose+convert: src[K][N] f32 -> dst[N][K] bf16 ----------------
__launch_bounds__(256)
__global__ void k_convT(const float* __restrict__ src, __bf16* __restrict__ dst, int K, int N){
  __shared__ float tile[32][33];
  int kb0 = blockIdx.x * 32, nb0 = blockIdx.y * 32;
  int tx = threadIdx.x & 31, ty = threadIdx.x >> 5;
  #pragma unroll
  for (int i = 0; i < 32; i += 8)
    tile[ty + i][tx] = src[(size_t)(kb0 + ty + i) * N + nb0 + tx];
  __syncthreads();
  #pragma unroll
  for (int i = 0; i < 32; i += 8)
    dst[(size_t)(nb0 + ty + i) * K + kb0 + tx] = (__bf16)tile[tx][ty + i];
}

// ---------------- bf16 MFMA GEMM: C[M][N] = A[M][K] @ BT[N][K]^T ----------------
// EPI: 0 = C f32 = AB (+bias); 1 = C f32 += AB + bias (residual);
//      2 = Cb bf16 = gelu(AB + bias);      3 = Cb bf16 = AB
template<int EPI>
__launch_bounds__(256)
__global__ void k_gemm_bt(const __bf16* __restrict__ A, const __bf16* __restrict__ BT,
                          const float* __restrict__ bias, float* __restrict__ C,
                          __bf16* __restrict__ Cb, int M, int Nn, int K){
  __shared__ __align__(16) __bf16 As[128 * 64];
  __shared__ __align__(16) __bf16 Bs[128 * 64];
  int t = threadIdx.x;
  int w = t >> 6, l = t & 63;
  int m0 = blockIdx.x * 128, n0 = blockIdx.y * 128;
  int wm = w >> 1, wn = w & 1;
  int lr = l & 15, lk = (l >> 4) * 8;
  f32x4 acc[4][4];
  #pragma unroll
  for (int i = 0; i < 4; ++i)
    #pragma unroll
    for (int j = 0; j < 4; ++j) acc[i][j] = 0.f;

  for (int kt = 0; kt < K; kt += 64){
    #pragma unroll
    for (int c = 0; c < 4; ++c){
      int chunk = c * 256 + w * 64 + l;
      int row = chunk >> 3, off = (chunk & 7) * 8;
      int ldsbase = (c * 256 + w * 64) * 8;
      gload16(A + (size_t)(m0 + row) * K + kt + off, (void*)(As + ldsbase));
      gload16(BT + (size_t)(n0 + row) * K + kt + off, (void*)(Bs + ldsbase));
    }
    asm volatile("s_waitcnt vmcnt(0)" ::: "memory");
    __syncthreads();
    #pragma unroll
    for (int kk = 0; kk < 2; ++kk){
      bf16x8 af[4], bfr[4];
      #pragma unroll
      for (int i = 0; i < 4; ++i)
        af[i] = *(const bf16x8*)&As[(wm * 64 + i * 16 + lr) * 64 + kk * 32 + lk];
      #pragma unroll
      for (int j = 0; j < 4; ++j)
        bfr[j] = *(const bf16x8*)&Bs[(wn * 64 + j * 16 + lr) * 64 + kk * 32 + lk];
      #pragma unroll
      for (int i = 0; i < 4; ++i)
        #pragma unroll
        for (int j = 0; j < 4; ++j)
          acc[i][j] = __builtin_amdgcn_mfma_f32_16x16x32_bf16(af[i], bfr[j], acc[i][j], 0, 0, 0);
    }
    __syncthreads();
  }
  int cr = (l >> 4) * 4;
  #pragma unroll
  for (int i = 0; i < 4; ++i){
    #pragma unroll
    for (int j = 0; j < 4; ++j){
      int row = m0 + wm * 64 + i * 16 + cr;
      int col = n0 + wn * 64 + j * 16 + lr;
      float bv = bias ? bias[col] : 0.f;
      #pragma unroll
      for (int r = 0; r < 4; ++r){
        float v = acc[i][j][r] + bv;
        if (EPI == 0) C[(size_t)(row + r) * Nn + col] = v;
        if (EPI == 1) C[(size_t)(row + r) * Nn + col] += v;
        if (EPI == 2) Cb[(size_t)(row + r) * Nn + col] = (__bf16)gelu_tanh(v);
        if (EPI == 3) Cb[(size_t)(row + r) * Nn + col] = (__bf16)v;
      }
    }
  }
}

// ---------------- diag[b,n,h] = 0.5*DN^2 * sum_d k^2 ----------------
__launch_bounds__(256)
__global__ void k_diag(const float* __restrict__ kb, float* __restrict__ diagg){
  int idx = blockIdx.x * 256 + threadIdx.x;     // 131072 = B*N*H
  int h = idx & (H_ - 1);
  int bn = idx >> 3;                            // b*N + n
  const float4* kr = (const float4*)(kb + (size_t)bn * INNER_ + h * DH_);
  float s0 = 0, s1 = 0, s2 = 0, s3 = 0;
  #pragma unroll
  for (int q = 0; q < 16; q++){
    float4 kk = kr[q];
    s0 += kk.x * kk.x; s1 += kk.y * kk.y; s2 += kk.z * kk.z; s3 += kk.w * kk.w;
  }
  diagg[idx] = 0.5f * DN_ * DN_ * ((s0 + s1) + (s2 + s3));
}

// ---------------- favor-k: f32 partial ctx and kfsum per ROWS_-row chunk ----------------
// stab dropped (cancels in o = qf@ctx / qf.kfsum); diag precomputed; pr pinned in VGPRs.
__launch_bounds__(256, 1)
__global__ void k_ctx(const float* __restrict__ kb, const __bf16* __restrict__ vb,
                      const float* __restrict__ proj, const float* __restrict__ diagg,
                      float* __restrict__ pctx, float* __restrict__ pkf){
  int c = blockIdx.x, h = blockIdx.y, b = blockIdx.z;
  int bh = b * H_ + h, t = threadIdx.x;
  const size_t rowbase = ((size_t)b * N_ + c * ROWS_) * INNER_ + h * DH_;
  const float* dgp = diagg + ((size_t)b * N_ + c * ROWS_) * H_ + h;
  float pr[64];
  #pragma unroll
  for (int q = 0; q < 16; q++){
    float4 p = *(const float4*)&proj[t * DH_ + q * 4];
    pr[4*q] = p.x; pr[4*q+1] = p.y; pr[4*q+2] = p.z; pr[4*q+3] = p.w;
  }
  // pin proj values into VGPRs: asm outputs cannot be rematerialized from memory
  #pragma unroll
  for (int q = 0; q < 64; q += 4)
    asm volatile("" : "+v"(pr[q]), "+v"(pr[q+1]), "+v"(pr[q+2]), "+v"(pr[q+3]));
  float cacc[64] = {};
  float ks = 0.f;
  for (int r = 0; r < ROWS_; ++r){
    const float4* kr = (const float4*)(kb + rowbase + (size_t)r * INNER_);
    float d0 = 0, d1 = 0, d2 = 0, d3 = 0;
    #pragma unroll
    for (int q = 0; q < 16; q++){
      float4 kk = kr[q];
      d0 += kk.x * pr[4*q]; d1 += kk.y * pr[4*q+1]; d2 += kk.z * pr[4*q+2]; d3 += kk.w * pr[4*q+3];
    }
    float dd = (d0 + d1) + (d2 + d3);
    float kf = RATIO_ * (__expf(dd * DN_ - dgp[(size_t)r * H_]) + KEPS_);
    ks += kf;
    const bf16x8* vr = (const bf16x8*)(vb + rowbase + (size_t)r * INNER_);
    #pragma unroll
    for (int q = 0; q < 8; q++){
      bf16x8 vv = vr[q];
      #pragma unroll
      for (int j = 0; j < 8; j++) cacc[q * 8 + j] += kf * (float)vv[j];
    }
  }
  float* pout = pctx + ((size_t)(c * 16 + bh) * 256 + t) * 64;
  #pragma unroll
  for (int q = 0; q < 16; q++)
    *(float4*)&pout[q * 4] = make_float4(cacc[4*q], cacc[4*q+1], cacc[4*q+2], cacc[4*q+3]);
  pkf[(size_t)(c * 16 + bh) * 256 + t] = ks;
}

__global__ void k_ctxred(const float* __restrict__ pctx, float* __restrict__ ctx){
  int i = blockIdx.x * 256 + threadIdx.x;   // 262144 outputs
  float s = 0.f;
  #pragma unroll
  for (int c = 0; c < CH_; ++c) s += pctx[(size_t)c * 262144 + i];
  ctx[i] = s;
}

__global__ void k_kfred(const float* __restrict__ pkf, float* __restrict__ kfsum){
  int i = blockIdx.x * 256 + threadIdx.x;   // 4096 outputs
  float s = 0.f;
  #pragma unroll
  for (int c = 0; c < CH_; ++c) s += pkf[c * 4096 + i];
  kfsum[i] = s;
}

// ---------------- favor-q fused: qf, denom, o = (qf @ ctx)/denom ----------------
__launch_bounds__(256)
__global__ void k_qo(const float* __restrict__ qb, const float* __restrict__ proj,
                     const float* __restrict__ ctxg, const float* __restrict__ kfsg, __bf16* __restrict__ ob){
  int h = blockIdx.y, b = blockIdx.z, n0 = blockIdx.x * 64;
  int bh = b * H_ + h, t = threadIdx.x;
  __shared__ float qsh[64][68];
  __shared__ float qfsh[64][260];
  __shared__ float ctxsh[128][64];
  __shared__ float kfs[256];
  __shared__ float diag[64], rmax[64], den[64];
  __shared__ float rpart[64][4];
  #pragma unroll
  for (int it = 0; it < 4; ++it){
    int lin = it * 256 + t, r = lin >> 4, q4 = lin & 15;
    *(float4*)&qsh[r][q4 * 4] = *(const float4*)&qb[(size_t)(b * N_ + n0 + r) * INNER_ + h * DH_ + q4 * 4];
  }
  kfs[t] = kfsg[bh * NB_ + t];
  float pr[64];
  #pragma unroll
  for (int q4 = 0; q4 < 16; q4++){
    float4 p = *(const float4*)&proj[t * DH_ + q4 * 4];
    pr[q4 * 4] = p.x; pr[q4 * 4 + 1] = p.y; pr[q4 * 4 + 2] = p.z; pr[q4 * 4 + 3] = p.w;
  }
  __syncthreads();
  if (t < 64){
    float s = 0.f;
    for (int d2 = 0; d2 < 64; d2++){ float qv = qsh[t][d2]; s += qv * qv; }
    diag[t] = 0.5f * DN_ * DN_ * s;
  }
  for (int r = 0; r < 64; r++){
    float d0 = 0, d1 = 0, d2 = 0, d3 = 0;
    #pragma unroll
    for (int q4 = 0; q4 < 16; q4++){
      float4 kk = *(const float4*)&qsh[r][q4 * 4];
      d0 += kk.x * pr[q4*4]; d1 += kk.y * pr[q4*4+1]; d2 += kk.z * pr[q4*4+2]; d3 += kk.w * pr[q4*4+3];
    }
    qfsh[r][t] = ((d0 + d1) + (d2 + d3)) * DN_;
  }
  __syncthreads();
  { int r = t >> 2, seg = t & 3; float mx = -3.4e38f;
    for (int i = 0; i < 64; i++) mx = fmaxf(mx, qfsh[r][seg * 64 + i]);
    rpart[r][seg] = mx; }
  __syncthreads();
  if (t < 64) rmax[t] = fmaxf(fmaxf(rpart[t][0], rpart[t][1]), fmaxf(rpart[t][2], rpart[t][3]));
  __syncthreads();
  for (int r = 0; r < 64; r++){
    qfsh[r][t] = RATIO_ * (__expf(qfsh[r][t] - diag[r] - rmax[r]) + KEPS_);
  }
  __syncthreads();
  { int r = t >> 2, seg = t & 3; float s = 0.f;
    for (int i = 0; i < 64; i++) s += qfsh[r][seg * 64 + i] * kfs[seg * 64 + i];
    rpart[r][seg] = s; }
  __syncthreads();
  if (t < 64) den[t] = rpart[t][0] + rpart[t][1] + rpart[t][2] + rpart[t][3];
  int dq = t & 15, rg = t >> 4, rb = rg * 4;
  float acc[4][4] = {};
  for (int ch = 0; ch < 2; ++ch){
    __syncthreads();
    #pragma unroll
    for (int it = 0; it < 8; ++it){
      int lin = it * 256 + t, m = lin >> 4, q4 = lin & 15;
      *(float4*)&ctxsh[m][q4 * 4] = *(const float4*)&ctxg[(size_t)(bh * NB_ + ch * 128 + m) * DH_ + q4 * 4];
    }
    __syncthreads();
    for (int m = 0; m < 128; m++){
      int mg = ch * 128 + m;
      float4 cv = *(const float4*)&ctxsh[m][dq * 4];
      float q0 = qfsh[rb][mg], q1 = qfsh[rb + 1][mg], q2 = qfsh[rb + 2][mg], q3 = qfsh[rb + 3][mg];
      acc[0][0] += q0 * cv.x; acc[0][1] += q0 * cv.y; acc[0][2] += q0 * cv.z; acc[0][3] += q0 * cv.w;
      acc[1][0] += q1 * cv.x; acc[1][1] += q1 * cv.y; acc[1][2] += q1 * cv.z; acc[1][3] += q1 * cv.w;
      acc[2][0] += q2 * cv.x; acc[2][1] += q2 * cv.y; acc[2][2] += q2 * cv.z; acc[2][3] += q2 * cv.w;
      acc[3][0] += q3 * cv.x; acc[3][1] += q3 * cv.y; acc[3][2] += q3 * cv.z; acc[3][3] += q3 * cv.w;
    }
  }
  #pragma unroll
  for (int rr = 0; rr < 4; rr++){
    float id = 1.f / den[rb + rr];
    __bf16* op = ob + (size_t)(b * N_ + n0 + rb + rr) * INNER_ + h * DH_ + dq * 4;
    op[0] = (__bf16)(acc[rr][0] * id); op[1] = (__bf16)(acc[rr][1] * id);
    op[2] = (__bf16)(acc[rr][2] * id); op[3] = (__bf16)(acc[rr][3] * id);
  }
}

// ---------------- final LN + head ----------------
__launch_bounds__(256)
__global__ void k_final(const float* __restrict__ z, const float* __restrict__ g, const float* __restrict__ bb,
                        const float* __restrict__ ow, const float* __restrict__ obias, float* __restrict__ out){
  int row = blockIdx.x, d = threadIdx.x;
  __shared__ float red[256];
  float v = z[row * DIM_ + d];
  red[d] = v; __syncthreads();
  #pragma unroll
  for (int s = 128; s > 0; s >>= 1){ if (d < s) red[d] += red[d + s]; __syncthreads(); }
  float mean = red[0] * (1.f / DIM_);
  __syncthreads();
  float c = v - mean;
  red[d] = c * c; __syncthreads();
  #pragma unroll
  for (int s = 128; s > 0; s >>= 1){ if (d < s) red[d] += red[d + s]; __syncthreads(); }
  float var = red[0] * (1.f / DIM_);
  __syncthreads();
  float yv = c * rsqrtf(var + LNEPS_) * g[d] + bb[d];
  red[d] = yv * ow[d]; __syncthreads();
  #pragma unroll
  for (int s = 128; s > 0; s >>= 1){ if (d < s) red[d] += red[d + s]; __syncthreads(); }
  if (d == 0) out[row] = red[0] + obias[0];
}

extern "C" void kernel_launch(void* const* d_in, const int* in_sizes, int n_in,
                              void* d_out, int out_size, void* d_ws, size_t ws_size,
                              hipStream_t stream){
  (void)in_sizes; (void)n_in; (void)out_size; (void)ws_size;
  const float* x      = (const float*)d_in[0];
  const float* mlp_w1 = (const float*)d_in[1];
  const float* mlp_b1 = (const float*)d_in[2];
  const float* mlp_w2 = (const float*)d_in[3];
  const float* mlp_b2 = (const float*)d_in[4];
  const float* pos    = (const float*)d_in[5];
  const float* gemb   = (const float*)d_in[6];
  const float* gw     = (const float*)d_in[7];
  const float* gb     = (const float*)d_in[8];
  const float* ew     = (const float*)d_in[9];
  const float* proj   = (const float*)d_in[10];
  const float* ln1g   = (const float*)d_in[11];
  const float* ln1b   = (const float*)d_in[12];
  const float* wq     = (const float*)d_in[13];
  const float* wk     = (const float*)d_in[14];
  const float* wv     = (const float*)d_in[15];
  const float* wo     = (const float*)d_in[16];
  const float* bo     = (const float*)d_in[17];
  const float* ln2g   = (const float*)d_in[18];
  const float* ln2b   = (const float*)d_in[19];
  const float* ffw1   = (const float*)d_in[20];
  const float* ffb1   = (const float*)d_in[21];
  const float* ffw2   = (const float*)d_in[22];
  const float* ffb2   = (const float*)d_in[23];
  const float* nfg    = (const float*)d_in[24];
  const float* nfb    = (const float*)d_in[25];
  const float* ow     = (const float*)d_in[26];
  const float* obias  = (const float*)d_in[27];
  const int*   ei     = (const int*)d_in[28];
  float* out = (float*)d_out;

  // workspace layout (floats). End = 37,114,112 fl = 148.46 MB (proven footprint)
  float* ws = (float*)d_ws;
  float*    deg   = ws;                       // 8,192
  float*    dinv  = ws + 8192;                // 8,192
  float*    kfsum = ws + 16640;               // 4,096
  float*    ctx   = ws + 20736;               // 262,144
  float*    diagg = ctx;                      // 131,072 (alias: dead once k_ctxred writes ctx)
  float*    z     = ws + 282880;              // 4,194,304
  float*    qb    = ws + 4477184;             // 8,388,608
  float*    kb    = ws + 12865792;            // 8,388,608
  __bf16*   vb    = (__bf16*)(ws + 21254400); // 8,388,608 elems (4,194,304 fl)
  __bf16*   ybf   = (__bf16*)(ws + 25448704); // 4,194,304 elems (2,097,152 fl)
  __bf16*   wT    = (__bf16*)(ws + 27545856); // 2,097,152 elems (1,048,576 fl)
  float*    pctx  = ws + 28594432;            // 8,388,608 (CH_=32 x 262,144)
  float*    agg   = pctx;                     // 2,097,152 (dead after k_z0; aliases pctx)
  float*    pkf   = ws + 36983040;            // 131,072 -> end 37,114,112 fl
  __bf16*   obf   = vb;                       // alias: v dead after k_ctx
  __bf16*   ffbf  = (__bf16*)qb;              // alias: q dead after k_qo (16.7M bf16 fits)

  hipMemsetAsync(deg, 0, N_ * sizeof(float), stream);
  hipMemsetAsync(agg, 0, (size_t)N_ * DIM_ * sizeof(float), stream);

  // weight convert+transpose to bf16 (per layer: wqT,wkT,wvT,woT,ffw1T,ffw2T)
  for (int l = 0; l < 2; ++l){
    __bf16* base = wT + (size_t)l * 1048576;
    k_convT<<<dim3(8, 16), 256, 0, stream>>>(wq + (size_t)l * DIM_ * INNER_, base + 0,      DIM_, INNER_);
    k_convT<<<dim3(8, 16), 256, 0, stream>>>(wk + (size_t)l * DIM_ * INNER_, base + 131072, DIM_, INNER_);
    k_convT<<<dim3(8, 16), 256, 0, stream>>>(wv + (size_t)l * DIM_ * INNER_, base + 262144, DIM_, INNER_);
    k_convT<<<dim3(16, 8), 256, 0, stream>>>(wo + (size_t)l * INNER_ * DIM_, base + 393216, INNER_, DIM_);
    k_convT<<<dim3(8, 32), 256, 0, stream>>>(ffw1 + (size_t)l * DIM_ * FF_,  base + 524288, DIM_, FF_);
    k_convT<<<dim3(32, 8), 256, 0, stream>>>(ffw2 + (size_t)l * FF_ * DIM_,  base + 786432, FF_, DIM_);
  }

  k_deg<<<E_ / 256, 256, 0, stream>>>(ei, ew, deg);
  k_dinv<<<N_ / 256, 256, 0, stream>>>(deg, dinv);
  k_agg<<<E_, 256, 0, stream>>>(ei, ew, dinv, gemb, agg);
  k_z0<<<N_ / 8, 256, 0, stream>>>(x, mlp_w1, mlp_b1, mlp_w2, mlp_b2, pos, agg, gw, gb, z);

  for (int l = 0; l < 2; ++l){
    __bf16* wqT = wT + (size_t)l * 1048576;
    __bf16* wkT = wqT + 131072;
    __bf16* wvT = wqT + 262144;
    __bf16* woT = wqT + 393216;
    __bf16* f1T = wqT + 524288;
    __bf16* f2T = wqT + 786432;
    k_ln<<<B_ * N_, 256, 0, stream>>>(z, ln1g + l * DIM_, ln1b + l * DIM_, ybf);
    k_gemm_bt<0><<<dim3(128, 4), 256, 0, stream>>>(ybf, wqT, nullptr, qb, nullptr, B_ * N_, INNER_, DIM_);
    k_gemm_bt<0><<<dim3(128, 4), 256, 0, stream>>>(ybf, wkT, nullptr, kb, nullptr, B_ * N_, INNER_, DIM_);
    k_gemm_bt<3><<<dim3(128, 4), 256, 0, stream>>>(ybf, wvT, nullptr, nullptr, vb, B_ * N_, INNER_, DIM_);
    k_diag<<<512, 256, 0, stream>>>(kb, diagg);
    k_ctx<<<dim3(CH_, H_, B_), 256, 0, stream>>>(kb, vb, proj, diagg, pctx, pkf);
    k_ctxred<<<1024, 256, 0, stream>>>(pctx, ctx);
    k_kfred<<<16, 256, 0, stream>>>(pkf, kfsum);
    k_qo<<<dim3(N_ / 64, H_, B_), 256, 0, stream>>>(qb, proj, ctx, kfsum, obf);
    k_gemm_bt<1><<<dim3(128, 2), 256, 0, stream>>>(obf, woT, bo + l * DIM_, z, nullptr, B_ * N_, DIM_, INNER_);
    k_ln<<<B_ * N_, 256, 0, stream>>>(z, ln2g + l * DIM_, ln2b + l * DIM_, ybf);
    k_gemm_bt<2><<<dim3(128, 8), 256, 0, stream>>>(ybf, f1T, ffb1 + l * FF_, nullptr, ffbf, B_ * N_, FF_, DIM_);
    k_gemm_bt<1><<<dim3(128, 2), 256, 0, stream>>>(ffbf, f2T, ffb2 + l * DIM_, z, nullptr, B_ * N_, DIM_, FF_);
  }
  k_final<<<B_ * N_, 256, 0, stream>>>(z, nfg, nfb, ow, obias, out);
}

// Round 11
// 1737.001 us; speedup vs baseline: 2.5197x; 1.1102x over previous
//
#include <hip/hip_runtime.h>
#include <cmath>

#define HD __device__ __forceinline__

constexpr int B_ = 2, N_ = 8192, DIM_ = 256, H_ = 8, DH_ = 64, INNER_ = 512, NB_ = 256, FF_ = 1024, E_ = 131072;
constexpr int CH_ = 32, ROWS_ = N_ / CH_;   // favor-k chunking: 32 chunks x 256 rows
constexpr float LNEPS_ = 1e-5f, KEPS_ = 1e-4f;
constexpr float DN_ = 0.35355339059327373f;   // 64^-0.25
constexpr float RATIO_ = 0.0625f;             // 256^-0.5

typedef __attribute__((ext_vector_type(8))) __bf16 bf16x8;
typedef __attribute__((ext_vector_type(4))) float f32x4;

HD float gelu_tanh(float x){
  float t = tanhf(0.7978845608028654f * (x + 0.044715f * x * x * x));
  return 0.5f * x * (1.f + t);
}
HD void gload16(const void* g, void* l){
  __builtin_amdgcn_global_load_lds((const __attribute__((address_space(1))) void*)g,
                                   (__attribute__((address_space(3))) void*)l, 16, 0, 0);
}

// ---------------- GNN ----------------
__global__ void k_deg(const int* __restrict__ ei, const float* __restrict__ ew, float* __restrict__ deg){
  int e = blockIdx.x * 256 + threadIdx.x;
  if (e < E_) atomicAdd(&deg[ei[E_ + e]], ew[e]);
}

__global__ void k_dinv(const float* __restrict__ deg, float* __restrict__ dinv){
  int i = blockIdx.x * 256 + threadIdx.x;
  if (i < N_){ float d = deg[i]; dinv[i] = d > 0.f ? rsqrtf(fmaxf(d, 1e-12f)) : 0.f; }
}

__global__ void k_agg(const int* __restrict__ ei, const float* __restrict__ ew, const float* __restrict__ dinv,
                      const float* __restrict__ gemb, float* __restrict__ agg){
  int e = blockIdx.x; int d = threadIdx.x;
  int r = ei[e], c = ei[E_ + e];
  float en = dinv[r] * ew[e] * dinv[c];
  atomicAdd(&agg[c * DIM_ + d], gemb[r * DIM_ + d] * en);
}

// ---------------- z0 = emb + pos + go ----------------
__launch_bounds__(256)
__global__ void k_z0(const float* __restrict__ x, const float* __restrict__ w1, const float* __restrict__ b1,
                     const float* __restrict__ w2, const float* __restrict__ b2,
                     const float* __restrict__ pos, const float* __restrict__ agg,
                     const float* __restrict__ gw, const float* __restrict__ gb, float* __restrict__ z){
  __shared__ float hsh[2][8][DIM_];
  __shared__ float ash[8][DIM_];
  int n0 = blockIdx.x * 8; int d = threadIdx.x;
  #pragma unroll
  for (int r = 0; r < 8; r++){
    ash[r][d] = agg[(n0 + r) * DIM_ + d];
    hsh[0][r][d] = fmaxf(x[n0 + r] * w1[d] + b1[d], 0.f);
    hsh[1][r][d] = fmaxf(x[N_ + n0 + r] * w1[d] + b1[d], 0.f);
  }
  __syncthreads();
  float go[8] = {}, e0[8] = {}, e1[8] = {};
  for (int k = 0; k < DIM_; k++){
    float wgk = gw[k * DIM_ + d], w2k = w2[k * DIM_ + d];
    #pragma unroll
    for (int r = 0; r < 8; r++){
      go[r] += ash[r][k] * wgk;
      e0[r] += hsh[0][r][k] * w2k;
      e1[r] += hsh[1][r][k] * w2k;
    }
  }
  #pragma unroll
  for (int r = 0; r < 8; r++){
    float base = go[r] + gb[d] + pos[(n0 + r) * DIM_ + d] + b2[d];
    z[(n0 + r) * DIM_ + d]      = e0[r] + base;
    z[(N_ + n0 + r) * DIM_ + d] = e1[r] + base;
  }
}

// ---------------- LayerNorm (bf16 out) ----------------
__launch_bounds__(256)
__global__ void k_ln(const float* __restrict__ z, const float* __restrict__ g, const float* __restrict__ bb,
                     __bf16* __restrict__ y){
  int row = blockIdx.x, d = threadIdx.x;
  __shared__ float red[256];
  float v = z[row * DIM_ + d];
  red[d] = v; __syncthreads();
  #pragma unroll
  for (int s = 128; s > 0; s >>= 1){ if (d < s) red[d] += red[d + s]; __syncthreads(); }
  float mean = red[0] * (1.f / DIM_);
  __syncthreads();
  float c = v - mean;
  red[d] = c * c; __syncthreads();
  #pragma unroll
  for (int s = 128; s > 0; s >>= 1){ if (d < s) red[d] += red[d + s]; __syncthreads(); }
  float var = red[0] * (1.f / DIM_);
  y[row * DIM_ + d] = (__bf16)(c * rsqrtf(var + LNEPS_) * g[d] + bb[d]);
}

// ---------------- weight transpose+convert: src[K][N] f32 -> dst[N][K] bf16 ----------------
__launch_bounds__(256)
__global__ void k_convT(const float* __restrict__ src, __bf16* __restrict__ dst, int K, int N){
  __shared__ float tile[32][33];
  int kb0 = blockIdx.x * 32, nb0 = blockIdx.y * 32;
  int tx = threadIdx.x & 31, ty = threadIdx.x >> 5;
  #pragma unroll
  for (int i = 0; i < 32; i += 8)
    tile[ty + i][tx] = src[(size_t)(kb0 + ty + i) * N + nb0 + tx];
  __syncthreads();
  #pragma unroll
  for (int i = 0; i < 32; i += 8)
    dst[(size_t)(nb0 + ty + i) * K + kb0 + tx] = (__bf16)tile[tx][ty + i];
}

// ---------------- bf16 MFMA GEMM: C[M][N] = A[M][K] @ BT[N][K]^T ----------------
// EPI: 0 = C f32 = AB (+bias); 1 = C f32 += AB + bias (residual);
//      2 = Cb bf16 = gelu(AB + bias);      3 = Cb bf16 = AB
template<int EPI>
__launch_bounds__(256)
__global__ void k_gemm_bt(const __bf16* __restrict__ A, const __bf16* __restrict__ BT,
                          const float* __restrict__ bias, float* __restrict__ C,
                          __bf16* __restrict__ Cb, int M, int Nn, int K){
  __shared__ __align__(16) __bf16 As[128 * 64];
  __shared__ __align__(16) __bf16 Bs[128 * 64];
  int t = threadIdx.x;
  int w = t >> 6, l = t & 63;
  int m0 = blockIdx.x * 128, n0 = blockIdx.y * 128;
  int wm = w >> 1, wn = w & 1;
  int lr = l & 15, lk = (l >> 4) * 8;
  f32x4 acc[4][4];
  #pragma unroll
  for (int i = 0; i < 4; ++i)
    #pragma unroll
    for (int j = 0; j < 4; ++j) acc[i][j] = 0.f;

  for (int kt = 0; kt < K; kt += 64){
    #pragma unroll
    for (int c = 0; c < 4; ++c){
      int chunk = c * 256 + w * 64 + l;
      int row = chunk >> 3, off = (chunk & 7) * 8;
      int ldsbase = (c * 256 + w * 64) * 8;
      gload16(A + (size_t)(m0 + row) * K + kt + off, (void*)(As + ldsbase));
      gload16(BT + (size_t)(n0 + row) * K + kt + off, (void*)(Bs + ldsbase));
    }
    asm volatile("s_waitcnt vmcnt(0)" ::: "memory");
    __syncthreads();
    #pragma unroll
    for (int kk = 0; kk < 2; ++kk){
      bf16x8 af[4], bfr[4];
      #pragma unroll
      for (int i = 0; i < 4; ++i)
        af[i] = *(const bf16x8*)&As[(wm * 64 + i * 16 + lr) * 64 + kk * 32 + lk];
      #pragma unroll
      for (int j = 0; j < 4; ++j)
        bfr[j] = *(const bf16x8*)&Bs[(wn * 64 + j * 16 + lr) * 64 + kk * 32 + lk];
      #pragma unroll
      for (int i = 0; i < 4; ++i)
        #pragma unroll
        for (int j = 0; j < 4; ++j)
          acc[i][j] = __builtin_amdgcn_mfma_f32_16x16x32_bf16(af[i], bfr[j], acc[i][j], 0, 0, 0);
    }
    __syncthreads();
  }
  int cr = (l >> 4) * 4;
  #pragma unroll
  for (int i = 0; i < 4; ++i){
    #pragma unroll
    for (int j = 0; j < 4; ++j){
      int row = m0 + wm * 64 + i * 16 + cr;
      int col = n0 + wn * 64 + j * 16 + lr;
      float bv = bias ? bias[col] : 0.f;
      #pragma unroll
      for (int r = 0; r < 4; ++r){
        float v = acc[i][j][r] + bv;
        if (EPI == 0) C[(size_t)(row + r) * Nn + col] = v;
        if (EPI == 1) C[(size_t)(row + r) * Nn + col] += v;
        if (EPI == 2) Cb[(size_t)(row + r) * Nn + col] = (__bf16)gelu_tanh(v);
        if (EPI == 3) Cb[(size_t)(row + r) * Nn + col] = (__bf16)v;
      }
    }
  }
}

// ---------------- diag[b,n,h] = 0.5*DN^2 * sum_d k^2 ----------------
__launch_bounds__(256)
__global__ void k_diag(const float* __restrict__ kb, float* __restrict__ diagg){
  int idx = blockIdx.x * 256 + threadIdx.x;     // 131072 = B*N*H
  int h = idx & (H_ - 1);
  int bn = idx >> 3;                            // b*N + n
  const float4* kr = (const float4*)(kb + (size_t)bn * INNER_ + h * DH_);
  float s0 = 0, s1 = 0, s2 = 0, s3 = 0;
  #pragma unroll
  for (int q = 0; q < 16; q++){
    float4 kk = kr[q];
    s0 += kk.x * kk.x; s1 += kk.y * kk.y; s2 += kk.z * kk.z; s3 += kk.w * kk.w;
  }
  diagg[idx] = 0.5f * DN_ * DN_ * ((s0 + s1) + (s2 + s3));
}

// ---------------- favor-k: f32 partial ctx and kfsum per ROWS_-row chunk ----------------
// stab dropped (cancels in o = qf@ctx / qf.kfsum); diag precomputed; pr pinned in VGPRs.
__launch_bounds__(256, 1)
__global__ void k_ctx(const float* __restrict__ kb, const __bf16* __restrict__ vb,
                      const float* __restrict__ proj, const float* __restrict__ diagg,
                      float* __restrict__ pctx, float* __restrict__ pkf){
  int c = blockIdx.x, h = blockIdx.y, b = blockIdx.z;
  int bh = b * H_ + h, t = threadIdx.x;
  const size_t rowbase = ((size_t)b * N_ + c * ROWS_) * INNER_ + h * DH_;
  const float* dgp = diagg + ((size_t)b * N_ + c * ROWS_) * H_ + h;
  float pr[64];
  #pragma unroll
  for (int q = 0; q < 16; q++){
    float4 p = *(const float4*)&proj[t * DH_ + q * 4];
    pr[4*q] = p.x; pr[4*q+1] = p.y; pr[4*q+2] = p.z; pr[4*q+3] = p.w;
  }
  // pin proj values into VGPRs: asm outputs cannot be rematerialized from memory
  #pragma unroll
  for (int q = 0; q < 64; q += 4)
    asm volatile("" : "+v"(pr[q]), "+v"(pr[q+1]), "+v"(pr[q+2]), "+v"(pr[q+3]));
  float cacc[64] = {};
  float ks = 0.f;
  for (int r = 0; r < ROWS_; ++r){
    const float4* kr = (const float4*)(kb + rowbase + (size_t)r * INNER_);
    float d0 = 0, d1 = 0, d2 = 0, d3 = 0;
    #pragma unroll
    for (int q = 0; q < 16; q++){
      float4 kk = kr[q];
      d0 += kk.x * pr[4*q]; d1 += kk.y * pr[4*q+1]; d2 += kk.z * pr[4*q+2]; d3 += kk.w * pr[4*q+3];
    }
    float dd = (d0 + d1) + (d2 + d3);
    float kf = RATIO_ * (__expf(dd * DN_ - dgp[(size_t)r * H_]) + KEPS_);
    ks += kf;
    const bf16x8* vr = (const bf16x8*)(vb + rowbase + (size_t)r * INNER_);
    #pragma unroll
    for (int q = 0; q < 8; q++){
      bf16x8 vv = vr[q];
      #pragma unroll
      for (int j = 0; j < 8; j++) cacc[q * 8 + j] += kf * (float)vv[j];
    }
  }
  float* pout = pctx + ((size_t)(c * 16 + bh) * 256 + t) * 64;
  #pragma unroll
  for (int q = 0; q < 16; q++)
    *(float4*)&pout[q * 4] = make_float4(cacc[4*q], cacc[4*q+1], cacc[4*q+2], cacc[4*q+3]);
  pkf[(size_t)(c * 16 + bh) * 256 + t] = ks;
}

__global__ void k_ctxred(const float* __restrict__ pctx, float* __restrict__ ctx){
  int i = blockIdx.x * 256 + threadIdx.x;   // 262144 outputs
  float s = 0.f;
  #pragma unroll
  for (int c = 0; c < CH_; ++c) s += pctx[(size_t)c * 262144 + i];
  ctx[i] = s;
}

__global__ void k_kfred(const float* __restrict__ pkf, float* __restrict__ kfsum){
  int i = blockIdx.x * 256 + threadIdx.x;   // 4096 outputs
  float s = 0.f;
  #pragma unroll
  for (int c = 0; c < CH_; ++c) s += pkf[c * 4096 + i];
  kfsum[i] = s;
}

// ---------------- favor-q fused: qf, denom, o = (qf @ ctx)/denom ----------------
// QBLK=32 rows/block (2 blocks/CU), qfsh stride 257 (bank-conflict-free o-loop)
__launch_bounds__(256)
__global__ void k_qo(const float* __restrict__ qb, const float* __restrict__ proj,
                     const float* __restrict__ ctxg, const float* __restrict__ kfsg, __bf16* __restrict__ ob){
  int h = blockIdx.y, b = blockIdx.z, n0 = blockIdx.x * 32;
  int bh = b * H_ + h, t = threadIdx.x;
  __shared__ float qsh[32][68];
  __shared__ float qfsh[32][257];
  __shared__ float ctxsh[128][64];
  __shared__ float kfs[256];
  __shared__ float diag[32], rmax[32], den[32];
  __shared__ float rpart[32][8];
  #pragma unroll
  for (int it = 0; it < 2; ++it){
    int lin = it * 256 + t, r = lin >> 4, q4 = lin & 15;
    *(float4*)&qsh[r][q4 * 4] = *(const float4*)&qb[(size_t)(b * N_ + n0 + r) * INNER_ + h * DH_ + q4 * 4];
  }
  kfs[t] = kfsg[bh * NB_ + t];
  float pr[64];
  #pragma unroll
  for (int q4 = 0; q4 < 16; q4++){
    float4 p = *(const float4*)&proj[t * DH_ + q4 * 4];
    pr[q4 * 4] = p.x; pr[q4 * 4 + 1] = p.y; pr[q4 * 4 + 2] = p.z; pr[q4 * 4 + 3] = p.w;
  }
  __syncthreads();
  if (t < 32){
    float s = 0.f;
    for (int d2 = 0; d2 < 64; d2++){ float qv = qsh[t][d2]; s += qv * qv; }
    diag[t] = 0.5f * DN_ * DN_ * s;
  }
  for (int r = 0; r < 32; r++){
    float d0 = 0, d1 = 0, d2 = 0, d3 = 0;
    #pragma unroll
    for (int q4 = 0; q4 < 16; q4++){
      float4 kk = *(const float4*)&qsh[r][q4 * 4];
      d0 += kk.x * pr[q4*4]; d1 += kk.y * pr[q4*4+1]; d2 += kk.z * pr[q4*4+2]; d3 += kk.w * pr[q4*4+3];
    }
    qfsh[r][t] = ((d0 + d1) + (d2 + d3)) * DN_;
  }
  __syncthreads();
  { int r = t >> 3, seg = t & 7; float mx = -3.4e38f;
    for (int i = 0; i < 32; i++) mx = fmaxf(mx, qfsh[r][seg * 32 + i]);
    rpart[r][seg] = mx; }
  __syncthreads();
  if (t < 32){
    float mx = rpart[t][0];
    #pragma unroll
    for (int s = 1; s < 8; s++) mx = fmaxf(mx, rpart[t][s]);
    rmax[t] = mx;
  }
  __syncthreads();
  for (int r = 0; r < 32; r++){
    qfsh[r][t] = RATIO_ * (__expf(qfsh[r][t] - diag[r] - rmax[r]) + KEPS_);
  }
  __syncthreads();
  { int r = t >> 3, seg = t & 7; float s = 0.f;
    for (int i = 0; i < 32; i++) s += qfsh[r][seg * 32 + i] * kfs[seg * 32 + i];
    rpart[r][seg] = s; }
  __syncthreads();
  if (t < 32){
    float s = 0.f;
    #pragma unroll
    for (int sg = 0; sg < 8; sg++) s += rpart[t][sg];
    den[t] = s;
  }
  int dq = t & 15, rg = t >> 4, rb = rg * 2;
  float acc[2][4] = {};
  for (int ch = 0; ch < 2; ++ch){
    __syncthreads();
    #pragma unroll
    for (int it = 0; it < 8; ++it){
      int lin = it * 256 + t, m = lin >> 4, q4 = lin & 15;
      *(float4*)&ctxsh[m][q4 * 4] = *(const float4*)&ctxg[(size_t)(bh * NB_ + ch * 128 + m) * DH_ + q4 * 4];
    }
    __syncthreads();
    for (int m = 0; m < 128; m++){
      int mg = ch * 128 + m;
      float4 cv = *(const float4*)&ctxsh[m][dq * 4];
      float q0 = qfsh[rb][mg], q1 = qfsh[rb + 1][mg];
      acc[0][0] += q0 * cv.x; acc[0][1] += q0 * cv.y; acc[0][2] += q0 * cv.z; acc[0][3] += q0 * cv.w;
      acc[1][0] += q1 * cv.x; acc[1][1] += q1 * cv.y; acc[1][2] += q1 * cv.z; acc[1][3] += q1 * cv.w;
    }
  }
  #pragma unroll
  for (int rr = 0; rr < 2; rr++){
    float id = 1.f / den[rb + rr];
    __bf16* op = ob + (size_t)(b * N_ + n0 + rb + rr) * INNER_ + h * DH_ + dq * 4;
    op[0] = (__bf16)(acc[rr][0] * id); op[1] = (__bf16)(acc[rr][1] * id);
    op[2] = (__bf16)(acc[rr][2] * id); op[3] = (__bf16)(acc[rr][3] * id);
  }
}

// ---------------- final LN + head ----------------
__launch_bounds__(256)
__global__ void k_final(const float* __restrict__ z, const float* __restrict__ g, const float* __restrict__ bb,
                        const float* __restrict__ ow, const float* __restrict__ obias, float* __restrict__ out){
  int row = blockIdx.x, d = threadIdx.x;
  __shared__ float red[256];
  float v = z[row * DIM_ + d];
  red[d] = v; __syncthreads();
  #pragma unroll
  for (int s = 128; s > 0; s >>= 1){ if (d < s) red[d] += red[d + s]; __syncthreads(); }
  float mean = red[0] * (1.f / DIM_);
  __syncthreads();
  float c = v - mean;
  red[d] = c * c; __syncthreads();
  #pragma unroll
  for (int s = 128; s > 0; s >>= 1){ if (d < s) red[d] += red[d + s]; __syncthreads(); }
  float var = red[0] * (1.f / DIM_);
  __syncthreads();
  float yv = c * rsqrtf(var + LNEPS_) * g[d] + bb[d];
  red[d] = yv * ow[d]; __syncthreads();
  #pragma unroll
  for (int s = 128; s > 0; s >>= 1){ if (d < s) red[d] += red[d + s]; __syncthreads(); }
  if (d == 0) out[row] = red[0] + obias[0];
}

extern "C" void kernel_launch(void* const* d_in, const int* in_sizes, int n_in,
                              void* d_out, int out_size, void* d_ws, size_t ws_size,
                              hipStream_t stream){
  (void)in_sizes; (void)n_in; (void)out_size; (void)ws_size;
  const float* x      = (const float*)d_in[0];
  const float* mlp_w1 = (const float*)d_in[1];
  const float* mlp_b1 = (const float*)d_in[2];
  const float* mlp_w2 = (const float*)d_in[3];
  const float* mlp_b2 = (const float*)d_in[4];
  const float* pos    = (const float*)d_in[5];
  const float* gemb   = (const float*)d_in[6];
  const float* gw     = (const float*)d_in[7];
  const float* gb     = (const float*)d_in[8];
  const float* ew     = (const float*)d_in[9];
  const float* proj   = (const float*)d_in[10];
  const float* ln1g   = (const float*)d_in[11];
  const float* ln1b   = (const float*)d_in[12];
  const float* wq     = (const float*)d_in[13];
  const float* wk     = (const float*)d_in[14];
  const float* wv     = (const float*)d_in[15];
  const float* wo     = (const float*)d_in[16];
  const float* bo     = (const float*)d_in[17];
  const float* ln2g   = (const float*)d_in[18];
  const float* ln2b   = (const float*)d_in[19];
  const float* ffw1   = (const float*)d_in[20];
  const float* ffb1   = (const float*)d_in[21];
  const float* ffw2   = (const float*)d_in[22];
  const float* ffb2   = (const float*)d_in[23];
  const float* nfg    = (const float*)d_in[24];
  const float* nfb    = (const float*)d_in[25];
  const float* ow     = (const float*)d_in[26];
  const float* obias  = (const float*)d_in[27];
  const int*   ei     = (const int*)d_in[28];
  float* out = (float*)d_out;

  // workspace layout (floats). End = 37,114,112 fl = 148.46 MB (proven footprint)
  float* ws = (float*)d_ws;
  float*    deg   = ws;                       // 8,192
  float*    dinv  = ws + 8192;                // 8,192
  float*    kfsum = ws + 16640;               // 4,096
  float*    ctx   = ws + 20736;               // 262,144
  float*    diagg = ctx;                      // 131,072 (alias: dead once k_ctxred writes ctx)
  float*    z     = ws + 282880;              // 4,194,304
  float*    qb    = ws + 4477184;             // 8,388,608
  float*    kb    = ws + 12865792;            // 8,388,608
  __bf16*   vb    = (__bf16*)(ws + 21254400); // 8,388,608 elems (4,194,304 fl)
  __bf16*   ybf   = (__bf16*)(ws + 25448704); // 4,194,304 elems (2,097,152 fl)
  __bf16*   wT    = (__bf16*)(ws + 27545856); // 2,097,152 elems (1,048,576 fl)
  float*    pctx  = ws + 28594432;            // 8,388,608 (CH_=32 x 262,144)
  float*    agg   = pctx;                     // 2,097,152 (dead after k_z0; aliases pctx)
  float*    pkf   = ws + 36983040;            // 131,072 -> end 37,114,112 fl
  __bf16*   obf   = vb;                       // alias: v dead after k_ctx
  __bf16*   ffbf  = (__bf16*)qb;              // alias: q dead after k_qo (16.7M bf16 fits)

  hipMemsetAsync(deg, 0, N_ * sizeof(float), stream);
  hipMemsetAsync(agg, 0, (size_t)N_ * DIM_ * sizeof(float), stream);

  // weight convert+transpose to bf16 (per layer: wqT,wkT,wvT,woT,ffw1T,ffw2T)
  for (int l = 0; l < 2; ++l){
    __bf16* base = wT + (size_t)l * 1048576;
    k_convT<<<dim3(8, 16), 256, 0, stream>>>(wq + (size_t)l * DIM_ * INNER_, base + 0,      DIM_, INNER_);
    k_convT<<<dim3(8, 16), 256, 0, stream>>>(wk + (size_t)l * DIM_ * INNER_, base + 131072, DIM_, INNER_);
    k_convT<<<dim3(8, 16), 256, 0, stream>>>(wv + (size_t)l * DIM_ * INNER_, base + 262144, DIM_, INNER_);
    k_convT<<<dim3(16, 8), 256, 0, stream>>>(wo + (size_t)l * INNER_ * DIM_, base + 393216, INNER_, DIM_);
    k_convT<<<dim3(8, 32), 256, 0, stream>>>(ffw1 + (size_t)l * DIM_ * FF_,  base + 524288, DIM_, FF_);
    k_convT<<<dim3(32, 8), 256, 0, stream>>>(ffw2 + (size_t)l * FF_ * DIM_,  base + 786432, FF_, DIM_);
  }

  k_deg<<<E_ / 256, 256, 0, stream>>>(ei, ew, deg);
  k_dinv<<<N_ / 256, 256, 0, stream>>>(deg, dinv);
  k_agg<<<E_, 256, 0, stream>>>(ei, ew, dinv, gemb, agg);
  k_z0<<<N_ / 8, 256, 0, stream>>>(x, mlp_w1, mlp_b1, mlp_w2, mlp_b2, pos, agg, gw, gb, z);

  for (int l = 0; l < 2; ++l){
    __bf16* wqT = wT + (size_t)l * 1048576;
    __bf16* wkT = wqT + 131072;
    __bf16* wvT = wqT + 262144;
    __bf16* woT = wqT + 393216;
    __bf16* f1T = wqT + 524288;
    __bf16* f2T = wqT + 786432;
    k_ln<<<B_ * N_, 256, 0, stream>>>(z, ln1g + l * DIM_, ln1b + l * DIM_, ybf);
    k_gemm_bt<0><<<dim3(128, 4), 256, 0, stream>>>(ybf, wqT, nullptr, qb, nullptr, B_ * N_, INNER_, DIM_);
    k_gemm_bt<0><<<dim3(128, 4), 256, 0, stream>>>(ybf, wkT, nullptr, kb, nullptr, B_ * N_, INNER_, DIM_);
    k_gemm_bt<3><<<dim3(128, 4), 256, 0, stream>>>(ybf, wvT, nullptr, nullptr, vb, B_ * N_, INNER_, DIM_);
    k_diag<<<512, 256, 0, stream>>>(kb, diagg);
    k_ctx<<<dim3(CH_, H_, B_), 256, 0, stream>>>(kb, vb, proj, diagg, pctx, pkf);
    k_ctxred<<<1024, 256, 0, stream>>>(pctx, ctx);
    k_kfred<<<16, 256, 0, stream>>>(pkf, kfsum);
    k_qo<<<dim3(N_ / 32, H_, B_), 256, 0, stream>>>(qb, proj, ctx, kfsum, obf);
    k_gemm_bt<1><<<dim3(128, 2), 256, 0, stream>>>(obf, woT, bo + l * DIM_, z, nullptr, B_ * N_, DIM_, INNER_);
    k_ln<<<B_ * N_, 256, 0, stream>>>(z, ln2g + l * DIM_, ln2b + l * DIM_, ybf);
    k_gemm_bt<2><<<dim3(128, 8), 256, 0, stream>>>(ybf, f1T, ffb1 + l * FF_, nullptr, ffbf, B_ * N_, FF_, DIM_);
    k_gemm_bt<1><<<dim3(128, 2), 256, 0, stream>>>(ffbf, f2T, ffb2 + l * DIM_, z, nullptr, B_ * N_, DIM_, FF_);
  }
  k_final<<<B_ * N_, 256, 0, stream>>>(z, nfg, nfb, ow, obias, out);
}